// Round 3
// baseline (249.546 us; speedup 1.0000x reference)
//
#include <hip/hip_runtime.h>
#include <hip/hip_bf16.h>
#include <cstdint>

typedef __bf16 bhalf;
typedef __bf16 bhalf8 __attribute__((ext_vector_type(8)));
typedef float f32x4 __attribute__((ext_vector_type(4)));

enum { EPI_Z2=0, EPI_UV=1, EPI_BIAS=2, EPI_QK=3, EPI_ATTN=4, EPI_PV=5, EPI_Y=6 };

// async global->LDS, 16B per lane, LDS dest = wave-uniform base + lane*16
__device__ __forceinline__ void gl_lds16(const bhalf* g, bhalf* l) {
  __builtin_amdgcn_global_load_lds(
      (const __attribute__((address_space(1))) unsigned int*)g,
      (__attribute__((address_space(3))) unsigned int*)l,
      16, 0, 0);
}
__device__ __forceinline__ void barrier_raw() { asm volatile("s_barrier" ::: "memory"); }
#define VMW(n) asm volatile("s_waitcnt vmcnt(" #n ")" ::: "memory")

// ---------------------------------------------------------------------------
// Deep-pipelined MFMA GEMM: out[m,n] = epi( sum_k A[m,k] * Bw[n,k] )
// 256xBN tile, BK=64, 8 waves (2x4), 4 phases/K-tile, counted vmcnt,
// k-slice-major LDS [2][rows][32] (64B rows -> conflict-free ds_read_b128).
// ---------------------------------------------------------------------------
template<int EPI, int BN>
__global__ void __launch_bounds__(512, 2)
gemm256(const bhalf* __restrict__ A, const bhalf* __restrict__ Bw,
        void* __restrict__ Out, void* __restrict__ Out2,
        const float* __restrict__ bias, const float* __restrict__ bias2,
        const bhalf* __restrict__ auxb, const float* __restrict__ auxf,
        int N, int K, long sA, long sB, long sO, long sAuxf,
        float scale, int rowshift)
{
  constexpr int WC = BN/4;          // cols per wave
  constexpr int JW = BN/64;         // j-frags per wave (4 or 2)
  constexpr int JQ = (JW>1 ? JW/2 : 1);
  constexpr int ABUF = 32768, BBUF = BN*128;
  constexpr int AKSL = 16384, BKSL = BN*64;
  __shared__ __align__(16) char lds[2*ABUF + 2*BBUF];

  // XCD-aware bijective swizzle (m204)
  const int gx = gridDim.x, gy = gridDim.y;
  const int nwg = gx*gy;
  const int flat = blockIdx.y*gx + blockIdx.x;
  const int q8 = nwg>>3, r8 = nwg&7, xcd = flat&7, o8 = flat>>3;
  const int wsw = (xcd<r8 ? xcd*(q8+1) : r8*(q8+1)+(xcd-r8)*q8) + o8;
  const int bx = wsw % gx, by = wsw / gx;
  const int m0 = by*256, n0 = bx*BN;
  const int bz = blockIdx.z;

  const bhalf* Ab = A + (long)bz*sA;
  const bhalf* Bb = Bw + (rowshift ? (long)(m0>>rowshift)*sB : (long)bz*sB);

  const int tid = threadIdx.x, wid = tid>>6, lane = tid&63;
  const int lm = lane&15, kq = lane>>4;
  const int wm = wid>>2, wn = wid&3;
  const int srow = lane>>2, sk = (lane&3)*8;

  char* la0 = lds;            char* la1 = lds + ABUF;
  char* lb0 = lds + 2*ABUF;   char* lb1 = lds + 2*ABUF + BBUF;

  f32x4 acc[8][JW];
  #pragma unroll
  for (int i=0;i<8;i++)
    #pragma unroll
    for (int j=0;j<JW;j++) acc[i][j] = f32x4{0.f,0.f,0.f,0.f};

  // stage A-half h (128 rows): wave stages rows h*128+wid*16..+16, both kslices
  auto stageA = [&](char* la, int h, int k0){
    #pragma unroll
    for (int ksl=0; ksl<2; ksl++){
      bhalf* d = (bhalf*)(la + ksl*AKSL + (h*128 + wid*16)*64);
      const bhalf* g = Ab + (long)(m0 + h*128 + wid*16 + srow)*K + (k0 + ksl*32 + sk);
      gl_lds16(g, d);
    }
  };
  auto stageB = [&](char* lb, int h, int k0){
    if constexpr (BN==256){
      #pragma unroll
      for (int ksl=0; ksl<2; ksl++){
        bhalf* d = (bhalf*)(lb + ksl*BKSL + (h*128 + wid*16)*64);
        const bhalf* g = Bb + (long)(n0 + h*128 + wid*16 + srow)*K + (k0 + ksl*32 + sk);
        gl_lds16(g, d);
      }
    } else {   // BN=128: half = 64 rows, 1 load/wave
      const int ksl = wid>>2, rg = wid&3;
      bhalf* d = (bhalf*)(lb + ksl*BKSL + (h*64 + rg*16)*64);
      const bhalf* g = Bb + (long)(n0 + h*64 + rg*16 + srow)*K + (k0 + ksl*32 + sk);
      gl_lds16(g, d);
    }
  };

  // one quadrant: mh selects global A-half, nh selects wave's j-half
  auto quad = [&](char* la, char* lb, int mh, int nh){
    bhalf8 af[4][2], bfr[JQ][2];
    #pragma unroll
    for (int i2=0;i2<4;i2++)
      #pragma unroll
      for (int ksl=0;ksl<2;ksl++)
        af[i2][ksl] = *(const bhalf8*)(la + ksl*AKSL + (mh*128 + wm*64 + i2*16 + lm)*64 + kq*16);
    #pragma unroll
    for (int j2=0;j2<JQ;j2++)
      #pragma unroll
      for (int ksl=0;ksl<2;ksl++)
        bfr[j2][ksl] = *(const bhalf8*)(lb + ksl*BKSL + (wn*WC + (nh*JQ+j2)*16 + lm)*64 + kq*16);
    __builtin_amdgcn_s_setprio(1);
    #pragma unroll
    for (int i2=0;i2<4;i2++)
      #pragma unroll
      for (int j2=0;j2<JQ;j2++)
        #pragma unroll
        for (int ksl=0;ksl<2;ksl++)
          acc[mh*4+i2][nh*JQ+j2] = __builtin_amdgcn_mfma_f32_16x16x32_bf16(
              af[i2][ksl], bfr[j2][ksl], acc[mh*4+i2][nh*JQ+j2], 0,0,0);
    __builtin_amdgcn_s_setprio(0);
  };

  const int NT = K>>6;
  // prologue: stage K-tile 0 (order B0,B1,A0,A1)
  stageB(lb0,0,0); stageB(lb0,1,0); stageA(la0,0,0); stageA(la0,1,0);

  for (int t=0; t<NT; ++t){
    const bool pre = (t+1)<NT;
    char* ca = (t&1)? la1: la0;  char* cb = (t&1)? lb1: lb0;
    char* na = (t&1)? la0: la1;  char* nb = (t&1)? lb0: lb1;
    const int k1 = (t+1)<<6;
    // ---- phase 0: quad(mh0,nh0); needs B0,B1,A0 of tile t landed
    if (pre) stageB(nb,0,k1);
    if constexpr (BN==256){ if (pre) { VMW(4); } else { VMW(2); } }
    else                  { if (pre) { VMW(3); } else { VMW(2); } }
    barrier_raw();
    quad(ca,cb,0,0);
    // ---- phase 1
    if (pre) stageB(nb,1,k1);
    quad(ca,cb,0,1);
    // ---- phase 2: needs A1 of tile t landed
    if (pre) stageA(na,0,k1);
    if constexpr (BN==256){ if (pre) { VMW(6); } else { VMW(0); } }
    else                  { if (pre) { VMW(4); } else { VMW(0); } }
    barrier_raw();
    quad(ca,cb,1,0);
    // ---- phase 3
    if (pre) stageA(na,1,k1);
    quad(ca,cb,1,1);
    barrier_raw();          // iteration boundary: all reads of (ca,cb) done
  }

  // ---- epilogue ----
  const long ob = (long)bz*sO;
  float rs[8][4];
  if constexpr (EPI==EPI_ATTN){
    #pragma unroll
    for (int i=0;i<8;i++)
      #pragma unroll
      for (int r=0;r<4;r++) rs[i][r]=0.f;
  }
  #pragma unroll
  for (int i=0;i<8;i++){
    const int rbase = m0 + (i>>2)*128 + wm*64 + (i&3)*16 + kq*4;
    #pragma unroll
    for (int j=0;j<JW;j++){
      const int colg = n0 + wn*WC + j*16 + lm;
      #pragma unroll
      for (int r=0;r<4;r++){
        const int rowg = rbase + r;
        float v = acc[i][j][r];
        if constexpr (EPI==EPI_ATTN){
          v *= scale; v = fmaxf(v,0.f); v = v*v;
          rs[i][r] += v;
          ((bhalf*)Out)[ob + (long)rowg*N + colg] = (bhalf)v;
        }
        if constexpr (EPI==EPI_PV){
          float den = auxf[rowg];
          v *= __builtin_amdgcn_rcpf(den + 1e-8f);
          v *= (float)auxb[(long)rowg*N + colg];
          ((bhalf*)Out)[(long)rowg*N + colg] = (bhalf)v;
        }
        if constexpr (EPI==EPI_UV){
          if (colg < 1024){
            v += bias[colg]; v = 1.f/(1.f + __expf(-v));
            ((bhalf*)Out)[(long)rowg*1024 + colg] = (bhalf)v;
          } else {
            v += bias2[colg-1024];
            ((bhalf*)Out2)[(long)rowg*1024 + colg-1024] = (bhalf)v;
          }
        }
        if constexpr (EPI==EPI_QK){
          if (colg < 512) ((bhalf*)Out)[(long)rowg*512 + colg] = (bhalf)v;
          else            ((bhalf*)Out2)[(long)rowg*512 + colg-512] = (bhalf)v;
        }
      }
    }
  }
  if constexpr (EPI==EPI_ATTN){
    float* rd = (float*)Out2;
    #pragma unroll
    for (int i=0;i<8;i++){
      const int rbase = m0 + (i>>2)*128 + wm*64 + (i&3)*16 + kq*4;
      #pragma unroll
      for (int r=0;r<4;r++){
        float s = rs[i][r];
        s += __shfl_xor(s,1); s += __shfl_xor(s,2);
        s += __shfl_xor(s,4); s += __shfl_xor(s,8);
        if (lm==0) atomicAdd(rd + (long)bz*sAuxf + rbase + r, s);
      }
    }
  }
  (void)scale; (void)bias; (void)bias2; (void)auxb; (void)auxf;
}

// ---------------------------------------------------------------------------
// m97-structure GEMM for the small-N (512) matmuls: z2, h, y
// ---------------------------------------------------------------------------
template<int EPI>
__global__ void __launch_bounds__(256, 2)
gemm_bt(const bhalf* __restrict__ A, const bhalf* __restrict__ Bw,
        void* __restrict__ Out, void* __restrict__ Out2,
        const float* __restrict__ bias, const float* __restrict__ bias2,
        const bhalf* __restrict__ auxb, const float* __restrict__ auxf,
        int M, int N, int K,
        long sA, long sB, long sO, long sAuxb, long sAuxf,
        float scale)
{
  const int bz = blockIdx.z;
  const int gx = gridDim.x, gy = gridDim.y;
  const int nwg = gx*gy;
  const int flat = blockIdx.y*gx + blockIdx.x;
  const int q8 = nwg>>3, r8 = nwg&7, xcd = flat&7, o8 = flat>>3;
  const int w = (xcd<r8 ? xcd*(q8+1) : r8*(q8+1)+(xcd-r8)*q8) + o8;
  const int bx = w % gx, by = w / gx;

  const bhalf* Ab = A + (long)bz*sA;
  const bhalf* Bb = Bw + (long)bz*sB;
  const int tid = threadIdx.x;
  const int wid = tid>>6, lane = tid&63;
  const int lm = lane&15, kq = lane>>4;
  const int wr = (wid>>1)*64, wc = (wid&1)*64;
  const int m0 = by*128, n0 = bx*128;

  __shared__ __align__(16) bhalf As[128*32];
  __shared__ __align__(16) bhalf Bs[128*32];

  f32x4 acc[4][4];
  #pragma unroll
  for (int i=0;i<4;i++)
    #pragma unroll
    for (int j=0;j<4;j++) acc[i][j] = f32x4{0.f,0.f,0.f,0.f};

  const int l4 = lane>>2;
  const int lk = (lane&3)*8;
  const bhalf* gA0 = Ab + (long)(m0 + wid*32 + l4)*K + lk;
  const bhalf* gA1 = gA0 + (long)16*K;
  const bhalf* gB0 = Bb + (long)(n0 + wid*32 + l4)*K + lk;
  const bhalf* gB1 = gB0 + (long)16*K;
  bhalf* lA0 = As + (wid*32)*32;
  bhalf* lA1 = As + (wid*32+16)*32;
  bhalf* lB0 = Bs + (wid*32)*32;
  bhalf* lB1 = Bs + (wid*32+16)*32;

  for (int k0=0; k0<K; k0+=32){
    __syncthreads();
    gl_lds16(gA0+k0, lA0);
    gl_lds16(gA1+k0, lA1);
    gl_lds16(gB0+k0, lB0);
    gl_lds16(gB1+k0, lB1);
    __syncthreads();
    bhalf8 af[4], bfr[4];
    #pragma unroll
    for (int i=0;i<4;i++){
      af[i]  = *(const bhalf8*)(As + (wr + i*16 + lm)*32 + kq*8);
      bfr[i] = *(const bhalf8*)(Bs + (wc + i*16 + lm)*32 + kq*8);
    }
    #pragma unroll
    for (int i=0;i<4;i++)
      #pragma unroll
      for (int j=0;j<4;j++)
        acc[i][j] = __builtin_amdgcn_mfma_f32_16x16x32_bf16(af[i], bfr[j], acc[i][j], 0,0,0);
  }

  #pragma unroll
  for (int i=0;i<4;i++){
    #pragma unroll
    for (int j=0;j<4;j++){
      const int colg = n0 + wc + j*16 + lm;
      #pragma unroll
      for (int r=0;r<4;r++){
        const int rowg = m0 + wr + i*16 + kq*4 + r;
        float v = acc[i][j][r];
        if constexpr (EPI==EPI_Z2){
          v += (float)auxb[(long)rowg*N + colg];
          ((bhalf*)Out)[(long)rowg*N + colg] = (bhalf)v;
        }
        if constexpr (EPI==EPI_BIAS){
          v += bias[colg];
          ((bhalf*)Out)[(long)rowg*N + colg] = (bhalf)v;
        }
        if constexpr (EPI==EPI_Y){
          ((bhalf*)Out)[(long)rowg*N + colg] = (bhalf)(v + bias[colg]);
        }
      }
    }
  }
  (void)scale; (void)M; (void)bias2; (void)Out2; (void)auxf; (void)sAuxb; (void)sAuxf;
}

// ---------------------------------------------------------------------------
struct CvtArgs { const float* src[7]; bhalf* dst[7]; int n[7]; };
__global__ void cvt_multi(CvtArgs a) {
  int seg = blockIdx.y;
  int i = (blockIdx.x*256 + threadIdx.x)*4;
  if (i >= a.n[seg]) return;
  float4 f = *(const float4*)(a.src[seg] + i);
  bhalf* d = a.dst[seg] + i;
  d[0]=(bhalf)f.x; d[1]=(bhalf)f.y; d[2]=(bhalf)f.z; d[3]=(bhalf)f.w;
}

__global__ void gn_part(const float* __restrict__ x, float* __restrict__ ps, float* __restrict__ pss) {
  int b = blockIdx.y;
  const float* xb = x + (long)b*(512*2048);
  float s=0.f, ss=0.f;
  #pragma unroll
  for (int it=0; it<8; it++){
    int idx = ((it*128 + blockIdx.x)*256 + threadIdx.x)*4;
    float4 f = *(const float4*)(xb + idx);
    s  += f.x+f.y+f.z+f.w;
    ss += f.x*f.x+f.y*f.y+f.z*f.z+f.w*f.w;
  }
  for (int off=32; off; off>>=1){ s += __shfl_xor(s,off); ss += __shfl_xor(ss,off); }
  __shared__ float ls[4], lss[4];
  int wid = threadIdx.x>>6, lane = threadIdx.x&63;
  if (lane==0){ ls[wid]=s; lss[wid]=ss; }
  __syncthreads();
  if (threadIdx.x==0){
    s = ls[0]+ls[1]+ls[2]+ls[3]; ss = lss[0]+lss[1]+lss[2]+lss[3];
    ps[b*128 + blockIdx.x] = s; pss[b*128 + blockIdx.x] = ss;
  }
}

__global__ void gn_final(const float* __restrict__ ps, const float* __restrict__ pss,
                         float* __restrict__ stats) {
  int b = blockIdx.x;
  float s = ps[b*128 + threadIdx.x], ss = pss[b*128 + threadIdx.x];
  for (int off=32; off; off>>=1){ s += __shfl_xor(s,off); ss += __shfl_xor(ss,off); }
  __shared__ float l0[2], l1[2];
  int wid = threadIdx.x>>6, lane = threadIdx.x&63;
  if (lane==0){ l0[wid]=s; l1[wid]=ss; }
  __syncthreads();
  if (threadIdx.x==0){
    s = l0[0]+l0[1]; ss = l1[0]+l1[1];
    float mean = s*(1.f/1048576.f);
    float var  = ss*(1.f/1048576.f) - mean*mean;
    stats[b*2] = mean; stats[b*2+1] = rsqrtf(var + 1e-8f);
  }
}

__global__ void norm_dw_T(const float* __restrict__ x, const float* __restrict__ stats,
                          const float* __restrict__ dw_w,
                          bhalf* __restrict__ zT, bhalf* __restrict__ dwT) {
  int b = blockIdx.z, n0 = blockIdx.x*32, c0 = blockIdx.y*32;
  float mean = stats[b*2], rstd = stats[b*2+1];
  __shared__ float zs[32][35];
  int tx = threadIdx.x, ty = threadIdx.y;
  #pragma unroll
  for (int r=0;r<4;r++){
    int c = c0 + ty + r*8;
    for (int cc=tx; cc<34; cc+=32){
      int n = n0 - 1 + cc;
      float v = 0.f;
      if (n>=0 && n<2048) v = (x[((long)b*512 + c)*2048 + n] - mean)*rstd;
      zs[ty + r*8][cc] = v;
    }
  }
  __syncthreads();
  float w0 = dw_w[(c0+tx)*3+0], w1 = dw_w[(c0+tx)*3+1], w2 = dw_w[(c0+tx)*3+2];
  #pragma unroll
  for (int r=0;r<4;r++){
    int ln = ty + r*8;
    float z = zs[tx][ln+1];
    float d = w0*zs[tx][ln] + w1*zs[tx][ln+1] + w2*zs[tx][ln+2];
    long o = ((long)b*2048 + n0 + ln)*512 + c0 + tx;
    zT[o] = (bhalf)z; dwT[o] = (bhalf)d;
  }
}

__global__ void transpose_bf16(const bhalf* __restrict__ in, bhalf* __restrict__ out,
                               int R, int C) {
  __shared__ bhalf t[32][33];
  int r0 = blockIdx.x*32, c0 = blockIdx.y*32;
  long ib = (long)blockIdx.z*R*C;
  int tx = threadIdx.x, ty = threadIdx.y;
  #pragma unroll
  for (int r=0;r<4;r++)
    t[ty + r*8][tx] = in[ib + (long)(r0 + ty + r*8)*C + c0 + tx];
  __syncthreads();
  #pragma unroll
  for (int r=0;r<4;r++)
    out[ib + (long)(c0 + ty + r*8)*R + r0 + tx] = t[tx][ty + r*8];
}

__global__ void final_add(const float* __restrict__ x, const bhalf* __restrict__ yT,
                          float* __restrict__ out) {
  __shared__ float t[32][33];
  int n0 = blockIdx.x*32, c0 = blockIdx.y*32, b = blockIdx.z;
  int tx = threadIdx.x, ty = threadIdx.y;
  #pragma unroll
  for (int r=0;r<4;r++)
    t[ty + r*8][tx] = (float)yT[((long)b*2048 + n0 + ty + r*8)*512 + c0 + tx];
  __syncthreads();
  #pragma unroll
  for (int r=0;r<4;r++){
    long idx = ((long)b*512 + c0 + ty + r*8)*2048 + n0 + tx;
    out[idx] = x[idx] + t[tx][ty + r*8];
  }
}

// ---------------------------------------------------------------------------
extern "C" void kernel_launch(void* const* d_in, const int* in_sizes, int n_in,
                              void* d_out, int out_size, void* d_ws, size_t ws_size,
                              hipStream_t stream) {
  (void)in_sizes; (void)n_in; (void)out_size; (void)ws_size;
  const float* x    = (const float*)d_in[0];
  const float* dw_w = (const float*)d_in[1];
  const float* pw_w = (const float*)d_in[2];
  const float* u_w  = (const float*)d_in[3];
  const float* u_b  = (const float*)d_in[4];
  const float* v_w  = (const float*)d_in[5];
  const float* v_b  = (const float*)d_in[6];
  const float* h_w  = (const float*)d_in[7];
  const float* h_b  = (const float*)d_in[8];
  const float* q_w  = (const float*)d_in[9];
  const float* k_w  = (const float*)d_in[10];
  const float* o_w  = (const float*)d_in[11];
  const float* o_b  = (const float*)d_in[12];
  float* out = (float*)d_out;

  char* ws = (char*)d_ws;
  size_t off = 0;
  auto alloc = [&](size_t bytes) -> void* {
    void* p = ws + off; off = (off + bytes + 255) & ~(size_t)255; return p;
  };

  float* ps    = (float*)alloc(4*128*4);
  float* pss   = (float*)alloc(4*128*4);
  float* stats = (float*)alloc(4*2*4);
  float* rden  = (float*)alloc(4*2048*4);
  bhalf* wb_pw = (bhalf*)alloc(512*512*2);
  bhalf* wb_uv = (bhalf*)alloc((size_t)2048*512*2);
  bhalf* wb_h  = (bhalf*)alloc(512*512*2);
  bhalf* wb_qk = (bhalf*)alloc((size_t)1024*512*2);
  bhalf* wb_o  = (bhalf*)alloc((size_t)512*1024*2);
  const size_t ACT = (size_t)4*2048*512;
  bhalf* zT   = (bhalf*)alloc(ACT*2);       // reused as qb
  bhalf* dwT  = (bhalf*)alloc(ACT*2);       // reused as kb
  bhalf* z2T  = (bhalf*)alloc(ACT*2);
  bhalf* ub   = (bhalf*)alloc(ACT*2*2);     // [B,N,1024]
  bhalf* vT   = (bhalf*)alloc(ACT*2*2);     // reused as yT (bf16 [B,N,512])
  bhalf* v_fm = (bhalf*)alloc(ACT*2*2);     // [B,1024,2048]
  bhalf* hb   = (bhalf*)alloc(ACT*2);
  bhalf* wsc  = (bhalf*)alloc((size_t)4*2048*2048*2);
  bhalf* uav  = (bhalf*)alloc(ACT*2*2);
  bhalf* qb = zT;  bhalf* kb = dwT;  bhalf* yT = vT;

  // 0. zero attention-denominator accumulators
  hipMemsetAsync(rden, 0, 4*2048*4, stream);

  // 1. weights -> bf16 (u|v and q|k concatenated)
  CvtArgs ca;
  ca.src[0]=pw_w; ca.dst[0]=wb_pw;           ca.n[0]=512*512;
  ca.src[1]=u_w;  ca.dst[1]=wb_uv;           ca.n[1]=1024*512;
  ca.src[2]=v_w;  ca.dst[2]=wb_uv+1024*512;  ca.n[2]=1024*512;
  ca.src[3]=h_w;  ca.dst[3]=wb_h;            ca.n[3]=512*512;
  ca.src[4]=q_w;  ca.dst[4]=wb_qk;           ca.n[4]=512*512;
  ca.src[5]=k_w;  ca.dst[5]=wb_qk+512*512;   ca.n[5]=512*512;
  ca.src[6]=o_w;  ca.dst[6]=wb_o;            ca.n[6]=512*1024;
  cvt_multi<<<dim3(512,7), 256, 0, stream>>>(ca);

  // 2-3. GroupNorm stats
  gn_part<<<dim3(128,4), 256, 0, stream>>>(x, ps, pss);
  gn_final<<<dim3(4), 128, 0, stream>>>(ps, pss, stats);

  // 4. normalize + dw conv + transpose -> zT, dwT
  norm_dw_T<<<dim3(64,16,4), dim3(32,8), 0, stream>>>(x, stats, dw_w, zT, dwT);

  const float iscl = 0.044194173824159216f;   // 1/sqrt(512)
  // 5. z2 = z + dw @ pw^T                (m97, N=512)
  gemm_bt<EPI_Z2><<<dim3(4,64,1), 256, 0, stream>>>(dwT, wb_pw, z2T, nullptr,
      nullptr, nullptr, zT, nullptr, 8192, 512, 512, 0,0,0,0,0, 0.f);
  // 6. [u|v] = z2 @ [u_w|v_w]^T + b      (256-tile pipelined)
  gemm256<EPI_UV,256><<<dim3(8,32,1), 512, 0, stream>>>(z2T, wb_uv, ub, vT,
      u_b, v_b, nullptr, nullptr, 2048, 512, 0,0,0,0, 0.f, 0);
  // 7. h = z2 @ h_w^T + h_b              (m97, N=512)
  gemm_bt<EPI_BIAS><<<dim3(4,64,1), 256, 0, stream>>>(z2T, wb_h, hb, nullptr,
      h_b, nullptr, nullptr, nullptr, 8192, 512, 512, 0,0,0,0,0, 0.f);
  // 8. [q|k] = h @ [q_w|k_w]^T           (256x128 pipelined)
  gemm256<EPI_QK,128><<<dim3(8,32,1), 512, 0, stream>>>(hb, wb_qk, qb, kb,
      nullptr, nullptr, nullptr, nullptr, 1024, 512, 0,0,0,0, 0.f, 0);
  // 9. v -> feature-major [B,1024,2048]
  transpose_bf16<<<dim3(64,32,4), dim3(32,8), 0, stream>>>(vT, v_fm, 2048, 1024);
  // 10. w = relu(q@k^T * scale)^2 + fused row-sum atomics into rden
  gemm256<EPI_ATTN,256><<<dim3(8,8,4), 512, 0, stream>>>(qb, kb, wsc, rden,
      nullptr, nullptr, nullptr, nullptr, 2048, 512,
      (long)2048*512, (long)2048*512, (long)2048*2048, 2048, iscl, 0);
  // 11. uav = u * (w @ v_fm^T) / (den+eps)   (256x128 pipelined, batch in M)
  gemm256<EPI_PV,128><<<dim3(8,32,1), 512, 0, stream>>>(wsc, v_fm, uav, nullptr,
      nullptr, nullptr, ub, rden, 1024, 2048,
      0, (long)1024*2048, 0, 0, 0.f, 11);
  // 12. yT = uav @ o_w^T + o_b (bf16 token-major)   (m97, N=512)
  gemm_bt<EPI_Y><<<dim3(4,64,1), 256, 0, stream>>>(uav, wb_o, yT, nullptr,
      o_b, nullptr, nullptr, nullptr, 8192, 512, 1024, 0,0,0,0,0, 0.f);
  // 13. out = x + yT^T
  final_add<<<dim3(64,16,4), dim3(32,8), 0, stream>>>(x, yT, out);
}

// Round 4
// 227.538 us; speedup vs baseline: 1.0967x; 1.0967x over previous
//
#include <hip/hip_runtime.h>
#include <hip/hip_bf16.h>
#include <cstdint>

typedef __bf16 bhalf;
typedef __bf16 bhalf8 __attribute__((ext_vector_type(8)));
typedef float f32x4 __attribute__((ext_vector_type(4)));

enum { EPI_Z2=0, EPI_UV=1, EPI_BIAS=2, EPI_QK=3, EPI_ATTN=4, EPI_PV=5, EPI_Y=6 };

// async global->LDS, 16B per lane, LDS dest = wave-uniform base + lane*16
__device__ __forceinline__ void gl_lds16(const bhalf* g, bhalf* l) {
  __builtin_amdgcn_global_load_lds(
      (const __attribute__((address_space(1))) unsigned int*)g,
      (__attribute__((address_space(3))) unsigned int*)l,
      16, 0, 0);
}
__device__ __forceinline__ void barrier_raw() { asm volatile("s_barrier" ::: "memory"); }
#define VMW(n) asm volatile("s_waitcnt vmcnt(" #n ")" ::: "memory")

// Bank swizzle: 16B chunk c of 64B row r lives at position c ^ ((r>>1)&3).
// Write side: pre-swizzled GLOBAL source (LDS dest linear, rule #21);
// read side: same XOR on ds_read address. Quad = (4r + c^((r>>1)&3)) mod 8
// covers all 8 bank-quads 2x over lm=0..15 -> 2-way (free, m136).

// ---------------------------------------------------------------------------
// Deep-pipelined MFMA GEMM: out[m,n] = epi( sum_k A[m,k] * Bw[n,k] )
// 256xBN tile, BK=64, 8 waves (2x4), 4 phases/K-tile, counted vmcnt,
// k-slice-major LDS [2][rows][32] + chunk-XOR bank swizzle, frag dedup.
// ---------------------------------------------------------------------------
template<int EPI, int BN>
__global__ void __launch_bounds__(512, 2)
gemm256(const bhalf* __restrict__ A, const bhalf* __restrict__ Bw,
        void* __restrict__ Out, void* __restrict__ Out2,
        const float* __restrict__ bias, const float* __restrict__ bias2,
        const bhalf* __restrict__ auxb, const float* __restrict__ auxf,
        int N, int K, long sA, long sB, long sO, long sAuxf,
        float scale, int rowshift)
{
  constexpr int WC = BN/4;          // cols per wave
  constexpr int JW = BN/64;         // j-frags per wave (4 or 2)
  constexpr int JQ = (JW>1 ? JW/2 : 1);
  constexpr int ABUF = 32768, BBUF = BN*128;
  constexpr int AKSL = 16384, BKSL = BN*64;
  __shared__ __align__(16) char lds[2*ABUF + 2*BBUF];

  // XCD-aware bijective swizzle (m204)
  const int gx = gridDim.x, gy = gridDim.y;
  const int nwg = gx*gy;
  const int flat = blockIdx.y*gx + blockIdx.x;
  const int q8 = nwg>>3, r8 = nwg&7, xcd = flat&7, o8 = flat>>3;
  const int wsw = (xcd<r8 ? xcd*(q8+1) : r8*(q8+1)+(xcd-r8)*q8) + o8;
  const int bx = wsw % gx, by = wsw / gx;
  const int m0 = by*256, n0 = bx*BN;
  const int bz = blockIdx.z;

  const bhalf* Ab = A + (long)bz*sA;
  const bhalf* Bb = Bw + (rowshift ? (long)(m0>>rowshift)*sB : (long)bz*sB);

  const int tid = threadIdx.x, wid = tid>>6, lane = tid&63;
  const int lm = lane&15, kq = lane>>4;
  const int wm = wid>>2, wn = wid&3;
  const int srow = lane>>2;
  // pre-swizzled global chunk offset for staging (elements)
  const int csw = ((lane&3) ^ ((lane>>3)&3)) * 8;
  // swizzled read chunk index
  const int kqs = kq ^ ((lm>>1)&3);

  char* la0 = lds;            char* la1 = lds + ABUF;
  char* lb0 = lds + 2*ABUF;   char* lb1 = lds + 2*ABUF + BBUF;

  f32x4 acc[8][JW];
  #pragma unroll
  for (int i=0;i<8;i++)
    #pragma unroll
    for (int j=0;j<JW;j++) acc[i][j] = f32x4{0.f,0.f,0.f,0.f};

  auto stageA = [&](char* la, int h, int k0){
    #pragma unroll
    for (int ksl=0; ksl<2; ksl++){
      bhalf* d = (bhalf*)(la + ksl*AKSL + (h*128 + wid*16)*64);
      const bhalf* g = Ab + (long)(m0 + h*128 + wid*16 + srow)*K + (k0 + ksl*32 + csw);
      gl_lds16(g, d);
    }
  };
  auto stageB = [&](char* lb, int h, int k0){
    if constexpr (BN==256){
      #pragma unroll
      for (int ksl=0; ksl<2; ksl++){
        bhalf* d = (bhalf*)(lb + ksl*BKSL + (h*128 + wid*16)*64);
        const bhalf* g = Bb + (long)(n0 + h*128 + wid*16 + srow)*K + (k0 + ksl*32 + csw);
        gl_lds16(g, d);
      }
    } else {   // BN=128: half = 64 rows, 1 load/wave
      const int ksl = wid>>2, rg = wid&3;
      bhalf* d = (bhalf*)(lb + ksl*BKSL + (h*64 + rg*16)*64);
      const bhalf* g = Bb + (long)(n0 + h*64 + rg*16 + srow)*K + (k0 + ksl*32 + csw);
      gl_lds16(g, d);
    }
  };

  bhalf8 af[4][2];      // A frags of current mh-half (reused across nh)
  bhalf8 bfr[JW][2];    // all B frags of the wave (reused across mh)

  auto readA = [&](char* la, int mh){
    #pragma unroll
    for (int i2=0;i2<4;i2++)
      #pragma unroll
      for (int ksl=0;ksl<2;ksl++)
        af[i2][ksl] = *(const bhalf8*)(la + ksl*AKSL + (mh*128 + wm*64 + i2*16 + lm)*64 + kqs*16);
  };
  auto readB = [&](char* lb, int nh){
    #pragma unroll
    for (int j2=0;j2<JQ;j2++)
      #pragma unroll
      for (int ksl=0;ksl<2;ksl++)
        bfr[nh*JQ+j2][ksl] = *(const bhalf8*)(lb + ksl*BKSL + (wn*WC + (nh*JQ+j2)*16 + lm)*64 + kqs*16);
  };
  auto domfma = [&](int mh, int nh){
    __builtin_amdgcn_s_setprio(1);
    #pragma unroll
    for (int i2=0;i2<4;i2++)
      #pragma unroll
      for (int j2=0;j2<JQ;j2++)
        #pragma unroll
        for (int ksl=0;ksl<2;ksl++)
          acc[mh*4+i2][nh*JQ+j2] = __builtin_amdgcn_mfma_f32_16x16x32_bf16(
              af[i2][ksl], bfr[nh*JQ+j2][ksl], acc[mh*4+i2][nh*JQ+j2], 0,0,0);
    __builtin_amdgcn_s_setprio(0);
  };

  const int NT = K>>6;
  // prologue: stage K-tile 0 (order B0,B1,A0,A1)
  stageB(lb0,0,0); stageB(lb0,1,0); stageA(la0,0,0); stageA(la0,1,0);

  for (int t=0; t<NT; ++t){
    const bool pre = (t+1)<NT;
    char* ca = (t&1)? la1: la0;  char* cb = (t&1)? lb1: lb0;
    char* na = (t&1)? la0: la1;  char* nb = (t&1)? lb0: lb1;
    const int k1 = (t+1)<<6;
    // ---- phase 0: needs B0,B1,A0 of tile t landed
    if (pre) stageB(nb,0,k1);
    if constexpr (BN==256){ if (pre) { VMW(4); } else { VMW(2); } }
    else                  { if (pre) { VMW(3); } else { VMW(2); } }
    barrier_raw();
    readA(ca,0); readB(cb,0);
    domfma(0,0);
    // ---- phase 1
    if (pre) stageB(nb,1,k1);
    readB(cb,1);
    domfma(0,1);
    // ---- phase 2: needs A1 of tile t landed
    if (pre) stageA(na,0,k1);
    if constexpr (BN==256){ if (pre) { VMW(6); } else { VMW(0); } }
    else                  { if (pre) { VMW(4); } else { VMW(0); } }
    barrier_raw();
    readA(ca,1);
    domfma(1,0);
    // ---- phase 3 (no reads: af/bfr all resident)
    if (pre) stageA(na,1,k1);
    domfma(1,1);
    barrier_raw();          // iteration boundary: all reads of (ca,cb) done
  }

  // ---- epilogue ----
  const long ob = (long)bz*sO;
  float rs[8][4];
  if constexpr (EPI==EPI_ATTN){
    #pragma unroll
    for (int i=0;i<8;i++)
      #pragma unroll
      for (int r=0;r<4;r++) rs[i][r]=0.f;
  }
  #pragma unroll
  for (int i=0;i<8;i++){
    const int rbase = m0 + (i>>2)*128 + wm*64 + (i&3)*16 + kq*4;
    #pragma unroll
    for (int j=0;j<JW;j++){
      const int colg = n0 + wn*WC + j*16 + lm;
      #pragma unroll
      for (int r=0;r<4;r++){
        const int rowg = rbase + r;
        float v = acc[i][j][r];
        if constexpr (EPI==EPI_ATTN){
          v *= scale; v = fmaxf(v,0.f); v = v*v;
          rs[i][r] += v;
          ((bhalf*)Out)[ob + (long)rowg*N + colg] = (bhalf)v;
        }
        if constexpr (EPI==EPI_PV){
          float den = auxf[rowg];
          v *= __builtin_amdgcn_rcpf(den + 1e-8f);
          v *= (float)auxb[(long)rowg*N + colg];
          ((bhalf*)Out)[(long)rowg*N + colg] = (bhalf)v;
        }
        if constexpr (EPI==EPI_UV){
          if (colg < 1024){
            v += bias[colg]; v = 1.f/(1.f + __expf(-v));
            ((bhalf*)Out)[(long)rowg*1024 + colg] = (bhalf)v;
          } else {
            v += bias2[colg-1024];
            ((bhalf*)Out2)[(long)rowg*1024 + colg-1024] = (bhalf)v;
          }
        }
        if constexpr (EPI==EPI_QK){
          if (colg < 512) ((bhalf*)Out)[(long)rowg*512 + colg] = (bhalf)v;
          else            ((bhalf*)Out2)[(long)rowg*512 + colg-512] = (bhalf)v;
        }
      }
    }
  }
  if constexpr (EPI==EPI_ATTN){
    float* rd = (float*)Out2;
    #pragma unroll
    for (int i=0;i<8;i++){
      const int rbase = m0 + (i>>2)*128 + wm*64 + (i&3)*16 + kq*4;
      #pragma unroll
      for (int r=0;r<4;r++){
        float s = rs[i][r];
        s += __shfl_xor(s,1); s += __shfl_xor(s,2);
        s += __shfl_xor(s,4); s += __shfl_xor(s,8);
        if (lm==0) atomicAdd(rd + (long)bz*sAuxf + rbase + r, s);
      }
    }
  }
  (void)scale; (void)bias; (void)bias2; (void)auxb; (void)auxf;
}

// ---------------------------------------------------------------------------
// m97-structure GEMM for the small-N (512) matmuls: z2, h, y (+ bank swizzle)
// ---------------------------------------------------------------------------
template<int EPI>
__global__ void __launch_bounds__(256, 2)
gemm_bt(const bhalf* __restrict__ A, const bhalf* __restrict__ Bw,
        void* __restrict__ Out, void* __restrict__ Out2,
        const float* __restrict__ bias, const float* __restrict__ bias2,
        const bhalf* __restrict__ auxb, const float* __restrict__ auxf,
        int M, int N, int K,
        long sA, long sB, long sO, long sAuxb, long sAuxf,
        float scale)
{
  const int bz = blockIdx.z;
  const int gx = gridDim.x, gy = gridDim.y;
  const int nwg = gx*gy;
  const int flat = blockIdx.y*gx + blockIdx.x;
  const int q8 = nwg>>3, r8 = nwg&7, xcd = flat&7, o8 = flat>>3;
  const int w = (xcd<r8 ? xcd*(q8+1) : r8*(q8+1)+(xcd-r8)*q8) + o8;
  const int bx = w % gx, by = w / gx;

  const bhalf* Ab = A + (long)bz*sA;
  const bhalf* Bb = Bw + (long)bz*sB;
  const int tid = threadIdx.x;
  const int wid = tid>>6, lane = tid&63;
  const int lm = lane&15, kq = lane>>4;
  const int wr = (wid>>1)*64, wc = (wid&1)*64;
  const int m0 = by*128, n0 = bx*128;
  const int kqs = kq ^ ((lm>>1)&3);

  __shared__ __align__(16) bhalf As[128*32];
  __shared__ __align__(16) bhalf Bs[128*32];

  f32x4 acc[4][4];
  #pragma unroll
  for (int i=0;i<4;i++)
    #pragma unroll
    for (int j=0;j<4;j++) acc[i][j] = f32x4{0.f,0.f,0.f,0.f};

  const int l4 = lane>>2;
  const int lk = ((lane&3) ^ ((lane>>3)&3))*8;   // pre-swizzled source chunk
  const bhalf* gA0 = Ab + (long)(m0 + wid*32 + l4)*K + lk;
  const bhalf* gA1 = gA0 + (long)16*K;
  const bhalf* gB0 = Bb + (long)(n0 + wid*32 + l4)*K + lk;
  const bhalf* gB1 = gB0 + (long)16*K;
  bhalf* lA0 = As + (wid*32)*32;
  bhalf* lA1 = As + (wid*32+16)*32;
  bhalf* lB0 = Bs + (wid*32)*32;
  bhalf* lB1 = Bs + (wid*32+16)*32;

  for (int k0=0; k0<K; k0+=32){
    __syncthreads();
    gl_lds16(gA0+k0, lA0);
    gl_lds16(gA1+k0, lA1);
    gl_lds16(gB0+k0, lB0);
    gl_lds16(gB1+k0, lB1);
    __syncthreads();
    bhalf8 af[4], bfr[4];
    #pragma unroll
    for (int i=0;i<4;i++){
      af[i]  = *(const bhalf8*)(As + (wr + i*16 + lm)*32 + kqs*8);
      bfr[i] = *(const bhalf8*)(Bs + (wc + i*16 + lm)*32 + kqs*8);
    }
    #pragma unroll
    for (int i=0;i<4;i++)
      #pragma unroll
      for (int j=0;j<4;j++)
        acc[i][j] = __builtin_amdgcn_mfma_f32_16x16x32_bf16(af[i], bfr[j], acc[i][j], 0,0,0);
  }

  #pragma unroll
  for (int i=0;i<4;i++){
    #pragma unroll
    for (int j=0;j<4;j++){
      const int colg = n0 + wc + j*16 + lm;
      #pragma unroll
      for (int r=0;r<4;r++){
        const int rowg = m0 + wr + i*16 + kq*4 + r;
        float v = acc[i][j][r];
        if constexpr (EPI==EPI_Z2){
          v += (float)auxb[(long)rowg*N + colg];
          ((bhalf*)Out)[(long)rowg*N + colg] = (bhalf)v;
        }
        if constexpr (EPI==EPI_BIAS){
          v += bias[colg];
          ((bhalf*)Out)[(long)rowg*N + colg] = (bhalf)v;
        }
        if constexpr (EPI==EPI_Y){
          ((bhalf*)Out)[(long)rowg*N + colg] = (bhalf)(v + bias[colg]);
        }
      }
    }
  }
  (void)scale; (void)M; (void)bias2; (void)Out2; (void)auxf; (void)sAuxb; (void)sAuxf;
}

// ---------------------------------------------------------------------------
struct CvtArgs { const float* src[7]; bhalf* dst[7]; int n[7]; };
__global__ void cvt_multi(CvtArgs a) {
  int seg = blockIdx.y;
  int i = (blockIdx.x*256 + threadIdx.x)*4;
  if (i >= a.n[seg]) return;
  float4 f = *(const float4*)(a.src[seg] + i);
  bhalf* d = a.dst[seg] + i;
  d[0]=(bhalf)f.x; d[1]=(bhalf)f.y; d[2]=(bhalf)f.z; d[3]=(bhalf)f.w;
}

__global__ void gn_part(const float* __restrict__ x, float* __restrict__ ps, float* __restrict__ pss) {
  int b = blockIdx.y;
  const float* xb = x + (long)b*(512*2048);
  float s=0.f, ss=0.f;
  #pragma unroll
  for (int it=0; it<8; it++){
    int idx = ((it*128 + blockIdx.x)*256 + threadIdx.x)*4;
    float4 f = *(const float4*)(xb + idx);
    s  += f.x+f.y+f.z+f.w;
    ss += f.x*f.x+f.y*f.y+f.z*f.z+f.w*f.w;
  }
  for (int off=32; off; off>>=1){ s += __shfl_xor(s,off); ss += __shfl_xor(ss,off); }
  __shared__ float ls[4], lss[4];
  int wid = threadIdx.x>>6, lane = threadIdx.x&63;
  if (lane==0){ ls[wid]=s; lss[wid]=ss; }
  __syncthreads();
  if (threadIdx.x==0){
    s = ls[0]+ls[1]+ls[2]+ls[3]; ss = lss[0]+lss[1]+lss[2]+lss[3];
    ps[b*128 + blockIdx.x] = s; pss[b*128 + blockIdx.x] = ss;
  }
}

__global__ void gn_final(const float* __restrict__ ps, const float* __restrict__ pss,
                         float* __restrict__ stats) {
  int b = blockIdx.x;
  float s = ps[b*128 + threadIdx.x], ss = pss[b*128 + threadIdx.x];
  for (int off=32; off; off>>=1){ s += __shfl_xor(s,off); ss += __shfl_xor(ss,off); }
  __shared__ float l0[2], l1[2];
  int wid = threadIdx.x>>6, lane = threadIdx.x&63;
  if (lane==0){ l0[wid]=s; l1[wid]=ss; }
  __syncthreads();
  if (threadIdx.x==0){
    s = l0[0]+l0[1]; ss = l1[0]+l1[1];
    float mean = s*(1.f/1048576.f);
    float var  = ss*(1.f/1048576.f) - mean*mean;
    stats[b*2] = mean; stats[b*2+1] = rsqrtf(var + 1e-8f);
  }
}

__global__ void norm_dw_T(const float* __restrict__ x, const float* __restrict__ stats,
                          const float* __restrict__ dw_w,
                          bhalf* __restrict__ zT, bhalf* __restrict__ dwT) {
  int b = blockIdx.z, n0 = blockIdx.x*32, c0 = blockIdx.y*32;
  float mean = stats[b*2], rstd = stats[b*2+1];
  __shared__ float zs[32][35];
  int tx = threadIdx.x, ty = threadIdx.y;
  #pragma unroll
  for (int r=0;r<4;r++){
    int c = c0 + ty + r*8;
    for (int cc=tx; cc<34; cc+=32){
      int n = n0 - 1 + cc;
      float v = 0.f;
      if (n>=0 && n<2048) v = (x[((long)b*512 + c)*2048 + n] - mean)*rstd;
      zs[ty + r*8][cc] = v;
    }
  }
  __syncthreads();
  float w0 = dw_w[(c0+tx)*3+0], w1 = dw_w[(c0+tx)*3+1], w2 = dw_w[(c0+tx)*3+2];
  #pragma unroll
  for (int r=0;r<4;r++){
    int ln = ty + r*8;
    float z = zs[tx][ln+1];
    float d = w0*zs[tx][ln] + w1*zs[tx][ln+1] + w2*zs[tx][ln+2];
    long o = ((long)b*2048 + n0 + ln)*512 + c0 + tx;
    zT[o] = (bhalf)z; dwT[o] = (bhalf)d;
  }
}

__global__ void transpose_bf16(const bhalf* __restrict__ in, bhalf* __restrict__ out,
                               int R, int C) {
  __shared__ bhalf t[32][33];
  int r0 = blockIdx.x*32, c0 = blockIdx.y*32;
  long ib = (long)blockIdx.z*R*C;
  int tx = threadIdx.x, ty = threadIdx.y;
  #pragma unroll
  for (int r=0;r<4;r++)
    t[ty + r*8][tx] = in[ib + (long)(r0 + ty + r*8)*C + c0 + tx];
  __syncthreads();
  #pragma unroll
  for (int r=0;r<4;r++)
    out[ib + (long)(c0 + ty + r*8)*R + r0 + tx] = t[tx][ty + r*8];
}

__global__ void final_add(const float* __restrict__ x, const bhalf* __restrict__ yT,
                          float* __restrict__ out) {
  __shared__ float t[32][33];
  int n0 = blockIdx.x*32, c0 = blockIdx.y*32, b = blockIdx.z;
  int tx = threadIdx.x, ty = threadIdx.y;
  #pragma unroll
  for (int r=0;r<4;r++)
    t[ty + r*8][tx] = (float)yT[((long)b*2048 + n0 + ty + r*8)*512 + c0 + tx];
  __syncthreads();
  #pragma unroll
  for (int r=0;r<4;r++){
    long idx = ((long)b*512 + c0 + ty + r*8)*2048 + n0 + tx;
    out[idx] = x[idx] + t[tx][ty + r*8];
  }
}

// ---------------------------------------------------------------------------
extern "C" void kernel_launch(void* const* d_in, const int* in_sizes, int n_in,
                              void* d_out, int out_size, void* d_ws, size_t ws_size,
                              hipStream_t stream) {
  (void)in_sizes; (void)n_in; (void)out_size; (void)ws_size;
  const float* x    = (const float*)d_in[0];
  const float* dw_w = (const float*)d_in[1];
  const float* pw_w = (const float*)d_in[2];
  const float* u_w  = (const float*)d_in[3];
  const float* u_b  = (const float*)d_in[4];
  const float* v_w  = (const float*)d_in[5];
  const float* v_b  = (const float*)d_in[6];
  const float* h_w  = (const float*)d_in[7];
  const float* h_b  = (const float*)d_in[8];
  const float* q_w  = (const float*)d_in[9];
  const float* k_w  = (const float*)d_in[10];
  const float* o_w  = (const float*)d_in[11];
  const float* o_b  = (const float*)d_in[12];
  float* out = (float*)d_out;

  char* ws = (char*)d_ws;
  size_t off = 0;
  auto alloc = [&](size_t bytes) -> void* {
    void* p = ws + off; off = (off + bytes + 255) & ~(size_t)255; return p;
  };

  float* ps    = (float*)alloc(4*128*4);
  float* pss   = (float*)alloc(4*128*4);
  float* stats = (float*)alloc(4*2*4);
  float* rden  = (float*)alloc(4*2048*4);
  bhalf* wb_pw = (bhalf*)alloc(512*512*2);
  bhalf* wb_uv = (bhalf*)alloc((size_t)2048*512*2);
  bhalf* wb_h  = (bhalf*)alloc(512*512*2);
  bhalf* wb_qk = (bhalf*)alloc((size_t)1024*512*2);
  bhalf* wb_o  = (bhalf*)alloc((size_t)512*1024*2);
  const size_t ACT = (size_t)4*2048*512;
  bhalf* zT   = (bhalf*)alloc(ACT*2);       // reused as qb
  bhalf* dwT  = (bhalf*)alloc(ACT*2);       // reused as kb
  bhalf* z2T  = (bhalf*)alloc(ACT*2);
  bhalf* ub   = (bhalf*)alloc(ACT*2*2);     // [B,N,1024]
  bhalf* vT   = (bhalf*)alloc(ACT*2*2);     // reused as yT (bf16 [B,N,512])
  bhalf* v_fm = (bhalf*)alloc(ACT*2*2);     // [B,1024,2048]
  bhalf* hb   = (bhalf*)alloc(ACT*2);
  bhalf* wsc  = (bhalf*)alloc((size_t)4*2048*2048*2);
  bhalf* uav  = (bhalf*)alloc(ACT*2*2);
  bhalf* qb = zT;  bhalf* kb = dwT;  bhalf* yT = vT;

  // 0. zero attention-denominator accumulators
  hipMemsetAsync(rden, 0, 4*2048*4, stream);

  // 1. weights -> bf16 (u|v and q|k concatenated)
  CvtArgs ca;
  ca.src[0]=pw_w; ca.dst[0]=wb_pw;           ca.n[0]=512*512;
  ca.src[1]=u_w;  ca.dst[1]=wb_uv;           ca.n[1]=1024*512;
  ca.src[2]=v_w;  ca.dst[2]=wb_uv+1024*512;  ca.n[2]=1024*512;
  ca.src[3]=h_w;  ca.dst[3]=wb_h;            ca.n[3]=512*512;
  ca.src[4]=q_w;  ca.dst[4]=wb_qk;           ca.n[4]=512*512;
  ca.src[5]=k_w;  ca.dst[5]=wb_qk+512*512;   ca.n[5]=512*512;
  ca.src[6]=o_w;  ca.dst[6]=wb_o;            ca.n[6]=512*1024;
  cvt_multi<<<dim3(512,7), 256, 0, stream>>>(ca);

  // 2-3. GroupNorm stats
  gn_part<<<dim3(128,4), 256, 0, stream>>>(x, ps, pss);
  gn_final<<<dim3(4), 128, 0, stream>>>(ps, pss, stats);

  // 4. normalize + dw conv + transpose -> zT, dwT
  norm_dw_T<<<dim3(64,16,4), dim3(32,8), 0, stream>>>(x, stats, dw_w, zT, dwT);

  const float iscl = 0.044194173824159216f;   // 1/sqrt(512)
  // 5. z2 = z + dw @ pw^T                (m97, N=512)
  gemm_bt<EPI_Z2><<<dim3(4,64,1), 256, 0, stream>>>(dwT, wb_pw, z2T, nullptr,
      nullptr, nullptr, zT, nullptr, 8192, 512, 512, 0,0,0,0,0, 0.f);
  // 6. [u|v] = z2 @ [u_w|v_w]^T + b      (256-tile pipelined)
  gemm256<EPI_UV,256><<<dim3(8,32,1), 512, 0, stream>>>(z2T, wb_uv, ub, vT,
      u_b, v_b, nullptr, nullptr, 2048, 512, 0,0,0,0, 0.f, 0);
  // 7. h = z2 @ h_w^T + h_b              (m97, N=512)
  gemm_bt<EPI_BIAS><<<dim3(4,64,1), 256, 0, stream>>>(z2T, wb_h, hb, nullptr,
      h_b, nullptr, nullptr, nullptr, 8192, 512, 512, 0,0,0,0,0, 0.f);
  // 8. [q|k] = h @ [q_w|k_w]^T           (256x128 pipelined)
  gemm256<EPI_QK,128><<<dim3(8,32,1), 512, 0, stream>>>(hb, wb_qk, qb, kb,
      nullptr, nullptr, nullptr, nullptr, 1024, 512, 0,0,0,0, 0.f, 0);
  // 9. v -> feature-major [B,1024,2048]
  transpose_bf16<<<dim3(64,32,4), dim3(32,8), 0, stream>>>(vT, v_fm, 2048, 1024);
  // 10. w = relu(q@k^T * scale)^2 + fused row-sum atomics into rden
  gemm256<EPI_ATTN,256><<<dim3(8,8,4), 512, 0, stream>>>(qb, kb, wsc, rden,
      nullptr, nullptr, nullptr, nullptr, 2048, 512,
      (long)2048*512, (long)2048*512, (long)2048*2048, 2048, iscl, 0);
  // 11. uav = u * (w @ v_fm^T) / (den+eps)   (256x128 pipelined, batch in M)
  gemm256<EPI_PV,128><<<dim3(8,32,1), 512, 0, stream>>>(wsc, v_fm, uav, nullptr,
      nullptr, nullptr, ub, rden, 1024, 2048,
      0, (long)1024*2048, 0, 0, 0.f, 11);
  // 12. yT = uav @ o_w^T + o_b (bf16 token-major)   (m97, N=512)
  gemm_bt<EPI_Y><<<dim3(4,64,1), 256, 0, stream>>>(uav, wb_o, yT, nullptr,
      o_b, nullptr, nullptr, nullptr, 8192, 512, 1024, 0,0,0,0,0, 0.f);
  // 13. out = x + yT^T
  final_add<<<dim3(64,16,4), dim3(32,8), 0, stream>>>(x, yT, out);
}

// Round 5
// 221.685 us; speedup vs baseline: 1.1257x; 1.0264x over previous
//
#include <hip/hip_runtime.h>
#include <hip/hip_bf16.h>
#include <cstdint>

typedef __bf16 bhalf;
typedef __bf16 bhalf8 __attribute__((ext_vector_type(8)));
typedef float f32x4 __attribute__((ext_vector_type(4)));

enum { EPI_Z2=0, EPI_UV=1, EPI_BIAS=2, EPI_QK=3, EPI_ATTN=4, EPI_PV=5, EPI_Y=6 };

// async global->LDS, 16B per lane, LDS dest = wave-uniform base + lane*16
__device__ __forceinline__ void gl_lds16(const bhalf* g, bhalf* l) {
  __builtin_amdgcn_global_load_lds(
      (const __attribute__((address_space(1))) unsigned int*)g,
      (__attribute__((address_space(3))) unsigned int*)l,
      16, 0, 0);
}
__device__ __forceinline__ void barrier_raw() { asm volatile("s_barrier" ::: "memory"); }
#define VMW(n) asm volatile("s_waitcnt vmcnt(" #n ")" ::: "memory")

// Bank swizzle (verified R4: SQ_LDS_BANK_CONFLICT == 0): 16B chunk c of 64B row
// r holds global chunk c ^ ((r>>1)&3). Write side: pre-swizzled GLOBAL source,
// LDS dest linear (rule #21); read side: kqs = kq ^ ((lm>>1)&3).

// ---------------------------------------------------------------------------
// Deep-pipelined MFMA GEMM: out[m,n] = epi( sum_k A[m,k] * Bw[n,k] )
// 256xBN tile, BK=32, 8 waves (2x4), 4 LDS buffers, 3-tiles-ahead prefetch,
// counted vmcnt (never 0 mid-loop).
// ---------------------------------------------------------------------------
template<int EPI, int BN>
__global__ void __launch_bounds__(512, 2)
gemm256(const bhalf* __restrict__ A, const bhalf* __restrict__ Bw,
        void* __restrict__ Out, void* __restrict__ Out2,
        const float* __restrict__ bias, const float* __restrict__ bias2,
        const bhalf* __restrict__ auxb, const float* __restrict__ auxf,
        int N, int K, long sA, long sB, long sO, long sAuxf,
        float scale, int rowshift)
{
  constexpr int JW = BN/64;            // j-frags per wave (4 or 2)
  constexpr int WC = BN/4;             // cols per wave
  constexpr int ABUF = 256*64;         // 16 KB
  constexpr int BBUF = BN*64;          // 16 or 8 KB
  constexpr int STRIDE = ABUF + BBUF;
  __shared__ __align__(16) char lds[4*STRIDE];

  // XCD-aware bijective swizzle (m204)
  const int gx = gridDim.x, gy = gridDim.y;
  const int nwg = gx*gy;
  const int flat = blockIdx.y*gx + blockIdx.x;
  const int q8 = nwg>>3, r8 = nwg&7, xcd = flat&7, o8 = flat>>3;
  const int wsw = (xcd<r8 ? xcd*(q8+1) : r8*(q8+1)+(xcd-r8)*q8) + o8;
  const int bx = wsw % gx, by = wsw / gx;
  const int m0 = by*256, n0 = bx*BN;
  const int bz = blockIdx.z;

  const bhalf* Ab = A + (long)bz*sA;
  const bhalf* Bb = Bw + (rowshift ? (long)(m0>>rowshift)*sB : (long)bz*sB);

  const int tid = threadIdx.x, wid = tid>>6, lane = tid&63;
  const int lm = lane&15, kq = lane>>4;
  const int wm = wid>>2, wn = wid&3;
  const int srow = lane>>2;
  const int csw = ((lane&3) ^ ((lane>>3)&3)) * 8;   // pre-swizzled source chunk
  const int kqs = kq ^ ((lm>>1)&3);                 // swizzled read chunk

  f32x4 acc[8][JW];
  #pragma unroll
  for (int i=0;i<8;i++)
    #pragma unroll
    for (int j=0;j<JW;j++) acc[i][j] = f32x4{0.f,0.f,0.f,0.f};

  auto stage = [&](int t){
    char* base = lds + (t&3)*STRIDE;
    const int k0 = t*32;
    #pragma unroll
    for (int c=0;c<2;c++){
      bhalf* d = (bhalf*)(base + (wid*32 + c*16)*64);
      gl_lds16(Ab + (long)(m0 + wid*32 + c*16 + srow)*K + k0 + csw, d);
    }
    if constexpr (BN==256){
      #pragma unroll
      for (int c=0;c<2;c++){
        bhalf* d = (bhalf*)(base + ABUF + (wid*32 + c*16)*64);
        gl_lds16(Bb + (long)(n0 + wid*32 + c*16 + srow)*K + k0 + csw, d);
      }
    } else {
      bhalf* d = (bhalf*)(base + ABUF + (wid*16)*64);
      gl_lds16(Bb + (long)(n0 + wid*16 + srow)*K + k0 + csw, d);
    }
  };

  auto compute = [&](int t){
    char* base = lds + (t&3)*STRIDE;
    bhalf8 af[8], bf[JW];
    #pragma unroll
    for (int i=0;i<8;i++)
      af[i] = *(const bhalf8*)(base + (wm*128 + i*16 + lm)*64 + kqs*16);
    #pragma unroll
    for (int j=0;j<JW;j++)
      bf[j] = *(const bhalf8*)(base + ABUF + (wn*WC + j*16 + lm)*64 + kqs*16);
    __builtin_amdgcn_s_setprio(1);
    #pragma unroll
    for (int i=0;i<8;i++)
      #pragma unroll
      for (int j=0;j<JW;j++)
        acc[i][j] = __builtin_amdgcn_mfma_f32_16x16x32_bf16(af[i], bf[j], acc[i][j], 0,0,0);
    __builtin_amdgcn_s_setprio(0);
  };

  const int NT = K>>5;                 // BK=32
  stage(0); stage(1); stage(2);        // 3 tiles in flight
  for (int t=0; t<NT; ++t){
    if (t+3<NT) stage(t+3);
    if constexpr (BN==256){            // L=4 loads/wave/tile
      if (t+3<NT)      { VMW(12); }
      else if (t+2<NT) { VMW(8);  }
      else if (t+1<NT) { VMW(4);  }
      else             { VMW(0);  }
    } else {                           // L=3
      if (t+3<NT)      { VMW(9); }
      else if (t+2<NT) { VMW(6); }
      else if (t+1<NT) { VMW(3); }
      else             { VMW(0); }
    }
    barrier_raw();                     // tile t fully in LDS for all waves
    compute(t);
    barrier_raw();                     // reads of tile t done before its buffer reuse
  }

  // ---- epilogue ----
  const long ob = (long)bz*sO;
  float rs[8][4];
  if constexpr (EPI==EPI_ATTN){
    #pragma unroll
    for (int i=0;i<8;i++)
      #pragma unroll
      for (int r=0;r<4;r++) rs[i][r]=0.f;
  }
  #pragma unroll
  for (int i=0;i<8;i++){
    const int rbase = m0 + wm*128 + i*16 + kq*4;
    #pragma unroll
    for (int j=0;j<JW;j++){
      const int colg = n0 + wn*WC + j*16 + lm;
      #pragma unroll
      for (int r=0;r<4;r++){
        const int rowg = rbase + r;
        float v = acc[i][j][r];
        if constexpr (EPI==EPI_ATTN){
          v *= scale; v = fmaxf(v,0.f); v = v*v;
          rs[i][r] += v;
          ((bhalf*)Out)[ob + (long)rowg*N + colg] = (bhalf)v;
        }
        if constexpr (EPI==EPI_PV){
          float den = auxf[rowg];
          v *= __builtin_amdgcn_rcpf(den + 1e-8f);
          v *= (float)auxb[(long)rowg*N + colg];
          ((bhalf*)Out)[(long)rowg*N + colg] = (bhalf)v;
        }
        if constexpr (EPI==EPI_UV){
          if (colg < 1024){
            v += bias[colg]; v = 1.f/(1.f + __expf(-v));
            ((bhalf*)Out)[(long)rowg*1024 + colg] = (bhalf)v;
          } else {
            v += bias2[colg-1024];
            ((bhalf*)Out2)[(long)rowg*1024 + colg-1024] = (bhalf)v;
          }
        }
        if constexpr (EPI==EPI_QK){
          if (colg < 512) ((bhalf*)Out)[(long)rowg*512 + colg] = (bhalf)v;
          else            ((bhalf*)Out2)[(long)rowg*512 + colg-512] = (bhalf)v;
        }
      }
    }
  }
  if constexpr (EPI==EPI_ATTN){
    float* rd = (float*)Out2;
    #pragma unroll
    for (int i=0;i<8;i++){
      const int rbase = m0 + wm*128 + i*16 + kq*4;
      #pragma unroll
      for (int r=0;r<4;r++){
        float s = rs[i][r];
        s += __shfl_xor(s,1); s += __shfl_xor(s,2);
        s += __shfl_xor(s,4); s += __shfl_xor(s,8);
        if (lm==0) atomicAdd(rd + (long)bz*sAuxf + rbase + r, s);
      }
    }
  }
  (void)scale; (void)bias; (void)bias2; (void)auxb; (void)auxf;
}

// ---------------------------------------------------------------------------
// Deep-pipelined 128x128 GEMM (z2, h, y): BK=32, 4 buffers, 3-ahead, 64KB LDS
// -> 2 blocks/CU.
// ---------------------------------------------------------------------------
template<int EPI>
__global__ void __launch_bounds__(256, 2)
gemm_bt(const bhalf* __restrict__ A, const bhalf* __restrict__ Bw,
        void* __restrict__ Out, void* __restrict__ Out2,
        const float* __restrict__ bias, const float* __restrict__ bias2,
        const bhalf* __restrict__ auxb, const float* __restrict__ auxf,
        int M, int N, int K,
        long sA, long sB, long sO, long sAuxb, long sAuxf,
        float scale)
{
  constexpr int ABUF = 128*64;        // 8 KB
  constexpr int STRIDE = 2*ABUF;      // 16 KB
  __shared__ __align__(16) char lds[4*STRIDE];

  const int bz = blockIdx.z;
  const int gx = gridDim.x, gy = gridDim.y;
  const int nwg = gx*gy;
  const int flat = blockIdx.y*gx + blockIdx.x;
  const int q8 = nwg>>3, r8 = nwg&7, xcd = flat&7, o8 = flat>>3;
  const int w = (xcd<r8 ? xcd*(q8+1) : r8*(q8+1)+(xcd-r8)*q8) + o8;
  const int bx = w % gx, by = w / gx;

  const bhalf* Ab = A + (long)bz*sA;
  const bhalf* Bb = Bw + (long)bz*sB;
  const int tid = threadIdx.x;
  const int wid = tid>>6, lane = tid&63;
  const int lm = lane&15, kq = lane>>4;
  const int wr = (wid>>1)*64, wc = (wid&1)*64;
  const int m0 = by*128, n0 = bx*128;
  const int srow = lane>>2;
  const int csw = ((lane&3) ^ ((lane>>3)&3))*8;
  const int kqs = kq ^ ((lm>>1)&3);

  f32x4 acc[4][4];
  #pragma unroll
  for (int i=0;i<4;i++)
    #pragma unroll
    for (int j=0;j<4;j++) acc[i][j] = f32x4{0.f,0.f,0.f,0.f};

  auto stage = [&](int t){
    char* base = lds + (t&3)*STRIDE;
    const int k0 = t*32;
    #pragma unroll
    for (int c=0;c<2;c++){
      bhalf* dA = (bhalf*)(base + (wid*32 + c*16)*64);
      gl_lds16(Ab + (long)(m0 + wid*32 + c*16 + srow)*K + k0 + csw, dA);
      bhalf* dB = (bhalf*)(base + ABUF + (wid*32 + c*16)*64);
      gl_lds16(Bb + (long)(n0 + wid*32 + c*16 + srow)*K + k0 + csw, dB);
    }
  };

  auto compute = [&](int t){
    char* base = lds + (t&3)*STRIDE;
    bhalf8 af[4], bf[4];
    #pragma unroll
    for (int i=0;i<4;i++)
      af[i] = *(const bhalf8*)(base + (wr + i*16 + lm)*64 + kqs*16);
    #pragma unroll
    for (int j=0;j<4;j++)
      bf[j] = *(const bhalf8*)(base + ABUF + (wc + j*16 + lm)*64 + kqs*16);
    __builtin_amdgcn_s_setprio(1);
    #pragma unroll
    for (int i=0;i<4;i++)
      #pragma unroll
      for (int j=0;j<4;j++)
        acc[i][j] = __builtin_amdgcn_mfma_f32_16x16x32_bf16(af[i], bf[j], acc[i][j], 0,0,0);
    __builtin_amdgcn_s_setprio(0);
  };

  const int NT = K>>5;
  stage(0); stage(1); stage(2);
  for (int t=0; t<NT; ++t){
    if (t+3<NT) stage(t+3);            // L=4 loads/wave/tile
    if (t+3<NT)      { VMW(12); }
    else if (t+2<NT) { VMW(8);  }
    else if (t+1<NT) { VMW(4);  }
    else             { VMW(0);  }
    barrier_raw();
    compute(t);
    barrier_raw();
  }

  #pragma unroll
  for (int i=0;i<4;i++){
    #pragma unroll
    for (int j=0;j<4;j++){
      const int colg = n0 + wc + j*16 + lm;
      #pragma unroll
      for (int r=0;r<4;r++){
        const int rowg = m0 + wr + i*16 + kq*4 + r;
        float v = acc[i][j][r];
        if constexpr (EPI==EPI_Z2){
          v += (float)auxb[(long)rowg*N + colg];
          ((bhalf*)Out)[(long)rowg*N + colg] = (bhalf)v;
        }
        if constexpr (EPI==EPI_BIAS){
          v += bias[colg];
          ((bhalf*)Out)[(long)rowg*N + colg] = (bhalf)v;
        }
        if constexpr (EPI==EPI_Y){
          ((bhalf*)Out)[(long)rowg*N + colg] = (bhalf)(v + bias[colg]);
        }
      }
    }
  }
  (void)scale; (void)M; (void)bias2; (void)Out2; (void)auxf; (void)sAuxb; (void)sAuxf;
}

// ---------------------------------------------------------------------------
struct CvtArgs { const float* src[7]; bhalf* dst[7]; int n[7]; };
__global__ void cvt_multi(CvtArgs a) {
  int seg = blockIdx.y;
  int i = (blockIdx.x*256 + threadIdx.x)*4;
  if (i >= a.n[seg]) return;
  float4 f = *(const float4*)(a.src[seg] + i);
  bhalf* d = a.dst[seg] + i;
  d[0]=(bhalf)f.x; d[1]=(bhalf)f.y; d[2]=(bhalf)f.z; d[3]=(bhalf)f.w;
}

__global__ void gn_part(const float* __restrict__ x, float* __restrict__ ps, float* __restrict__ pss) {
  int b = blockIdx.y;
  const float* xb = x + (long)b*(512*2048);
  float s=0.f, ss=0.f;
  #pragma unroll
  for (int it=0; it<8; it++){
    int idx = ((it*128 + blockIdx.x)*256 + threadIdx.x)*4;
    float4 f = *(const float4*)(xb + idx);
    s  += f.x+f.y+f.z+f.w;
    ss += f.x*f.x+f.y*f.y+f.z*f.z+f.w*f.w;
  }
  for (int off=32; off; off>>=1){ s += __shfl_xor(s,off); ss += __shfl_xor(ss,off); }
  __shared__ float ls[4], lss[4];
  int wid = threadIdx.x>>6, lane = threadIdx.x&63;
  if (lane==0){ ls[wid]=s; lss[wid]=ss; }
  __syncthreads();
  if (threadIdx.x==0){
    s = ls[0]+ls[1]+ls[2]+ls[3]; ss = lss[0]+lss[1]+lss[2]+lss[3];
    ps[b*128 + blockIdx.x] = s; pss[b*128 + blockIdx.x] = ss;
  }
}

__global__ void gn_final(const float* __restrict__ ps, const float* __restrict__ pss,
                         float* __restrict__ stats) {
  int b = blockIdx.x;
  float s = ps[b*128 + threadIdx.x], ss = pss[b*128 + threadIdx.x];
  for (int off=32; off; off>>=1){ s += __shfl_xor(s,off); ss += __shfl_xor(ss,off); }
  __shared__ float l0[2], l1[2];
  int wid = threadIdx.x>>6, lane = threadIdx.x&63;
  if (lane==0){ l0[wid]=s; l1[wid]=ss; }
  __syncthreads();
  if (threadIdx.x==0){
    s = l0[0]+l0[1]; ss = l1[0]+l1[1];
    float mean = s*(1.f/1048576.f);
    float var  = ss*(1.f/1048576.f) - mean*mean;
    stats[b*2] = mean; stats[b*2+1] = rsqrtf(var + 1e-8f);
  }
}

__global__ void norm_dw_T(const float* __restrict__ x, const float* __restrict__ stats,
                          const float* __restrict__ dw_w,
                          bhalf* __restrict__ zT, bhalf* __restrict__ dwT) {
  int b = blockIdx.z, n0 = blockIdx.x*32, c0 = blockIdx.y*32;
  float mean = stats[b*2], rstd = stats[b*2+1];
  __shared__ float zs[32][35];
  int tx = threadIdx.x, ty = threadIdx.y;
  #pragma unroll
  for (int r=0;r<4;r++){
    int c = c0 + ty + r*8;
    for (int cc=tx; cc<34; cc+=32){
      int n = n0 - 1 + cc;
      float v = 0.f;
      if (n>=0 && n<2048) v = (x[((long)b*512 + c)*2048 + n] - mean)*rstd;
      zs[ty + r*8][cc] = v;
    }
  }
  __syncthreads();
  float w0 = dw_w[(c0+tx)*3+0], w1 = dw_w[(c0+tx)*3+1], w2 = dw_w[(c0+tx)*3+2];
  #pragma unroll
  for (int r=0;r<4;r++){
    int ln = ty + r*8;
    float z = zs[tx][ln+1];
    float d = w0*zs[tx][ln] + w1*zs[tx][ln+1] + w2*zs[tx][ln+2];
    long o = ((long)b*2048 + n0 + ln)*512 + c0 + tx;
    zT[o] = (bhalf)z; dwT[o] = (bhalf)d;
  }
}

__global__ void transpose_bf16(const bhalf* __restrict__ in, bhalf* __restrict__ out,
                               int R, int C) {
  __shared__ bhalf t[32][33];
  int r0 = blockIdx.x*32, c0 = blockIdx.y*32;
  long ib = (long)blockIdx.z*R*C;
  int tx = threadIdx.x, ty = threadIdx.y;
  #pragma unroll
  for (int r=0;r<4;r++)
    t[ty + r*8][tx] = in[ib + (long)(r0 + ty + r*8)*C + c0 + tx];
  __syncthreads();
  #pragma unroll
  for (int r=0;r<4;r++)
    out[ib + (long)(c0 + ty + r*8)*R + r0 + tx] = t[tx][ty + r*8];
}

__global__ void final_add(const float* __restrict__ x, const bhalf* __restrict__ yT,
                          float* __restrict__ out) {
  __shared__ float t[32][33];
  int n0 = blockIdx.x*32, c0 = blockIdx.y*32, b = blockIdx.z;
  int tx = threadIdx.x, ty = threadIdx.y;
  #pragma unroll
  for (int r=0;r<4;r++)
    t[ty + r*8][tx] = (float)yT[((long)b*2048 + n0 + ty + r*8)*512 + c0 + tx];
  __syncthreads();
  #pragma unroll
  for (int r=0;r<4;r++){
    long idx = ((long)b*512 + c0 + ty + r*8)*2048 + n0 + tx;
    out[idx] = x[idx] + t[tx][ty + r*8];
  }
}

// ---------------------------------------------------------------------------
extern "C" void kernel_launch(void* const* d_in, const int* in_sizes, int n_in,
                              void* d_out, int out_size, void* d_ws, size_t ws_size,
                              hipStream_t stream) {
  (void)in_sizes; (void)n_in; (void)out_size; (void)ws_size;
  const float* x    = (const float*)d_in[0];
  const float* dw_w = (const float*)d_in[1];
  const float* pw_w = (const float*)d_in[2];
  const float* u_w  = (const float*)d_in[3];
  const float* u_b  = (const float*)d_in[4];
  const float* v_w  = (const float*)d_in[5];
  const float* v_b  = (const float*)d_in[6];
  const float* h_w  = (const float*)d_in[7];
  const float* h_b  = (const float*)d_in[8];
  const float* q_w  = (const float*)d_in[9];
  const float* k_w  = (const float*)d_in[10];
  const float* o_w  = (const float*)d_in[11];
  const float* o_b  = (const float*)d_in[12];
  float* out = (float*)d_out;

  char* ws = (char*)d_ws;
  size_t off = 0;
  auto alloc = [&](size_t bytes) -> void* {
    void* p = ws + off; off = (off + bytes + 255) & ~(size_t)255; return p;
  };

  float* ps    = (float*)alloc(4*128*4);
  float* pss   = (float*)alloc(4*128*4);
  float* stats = (float*)alloc(4*2*4);
  float* rden  = (float*)alloc(4*2048*4);
  bhalf* wb_pw = (bhalf*)alloc(512*512*2);
  bhalf* wb_uv = (bhalf*)alloc((size_t)2048*512*2);
  bhalf* wb_h  = (bhalf*)alloc(512*512*2);
  bhalf* wb_qk = (bhalf*)alloc((size_t)1024*512*2);
  bhalf* wb_o  = (bhalf*)alloc((size_t)512*1024*2);
  const size_t ACT = (size_t)4*2048*512;
  bhalf* zT   = (bhalf*)alloc(ACT*2);       // reused as qb
  bhalf* dwT  = (bhalf*)alloc(ACT*2);       // reused as kb
  bhalf* z2T  = (bhalf*)alloc(ACT*2);
  bhalf* ub   = (bhalf*)alloc(ACT*2*2);     // [B,N,1024]
  bhalf* vT   = (bhalf*)alloc(ACT*2*2);     // reused as yT (bf16 [B,N,512])
  bhalf* v_fm = (bhalf*)alloc(ACT*2*2);     // [B,1024,2048]
  bhalf* hb   = (bhalf*)alloc(ACT*2);
  bhalf* wsc  = (bhalf*)alloc((size_t)4*2048*2048*2);
  bhalf* uav  = (bhalf*)alloc(ACT*2*2);
  bhalf* qb = zT;  bhalf* kb = dwT;  bhalf* yT = vT;

  // 0. zero attention-denominator accumulators
  hipMemsetAsync(rden, 0, 4*2048*4, stream);

  // 1. weights -> bf16 (u|v and q|k concatenated)
  CvtArgs ca;
  ca.src[0]=pw_w; ca.dst[0]=wb_pw;           ca.n[0]=512*512;
  ca.src[1]=u_w;  ca.dst[1]=wb_uv;           ca.n[1]=1024*512;
  ca.src[2]=v_w;  ca.dst[2]=wb_uv+1024*512;  ca.n[2]=1024*512;
  ca.src[3]=h_w;  ca.dst[3]=wb_h;            ca.n[3]=512*512;
  ca.src[4]=q_w;  ca.dst[4]=wb_qk;           ca.n[4]=512*512;
  ca.src[5]=k_w;  ca.dst[5]=wb_qk+512*512;   ca.n[5]=512*512;
  ca.src[6]=o_w;  ca.dst[6]=wb_o;            ca.n[6]=512*1024;
  cvt_multi<<<dim3(512,7), 256, 0, stream>>>(ca);

  // 2-3. GroupNorm stats
  gn_part<<<dim3(128,4), 256, 0, stream>>>(x, ps, pss);
  gn_final<<<dim3(4), 128, 0, stream>>>(ps, pss, stats);

  // 4. normalize + dw conv + transpose -> zT, dwT
  norm_dw_T<<<dim3(64,16,4), dim3(32,8), 0, stream>>>(x, stats, dw_w, zT, dwT);

  const float iscl = 0.044194173824159216f;   // 1/sqrt(512)
  // 5. z2 = z + dw @ pw^T                (128^2 deep-pipe)
  gemm_bt<EPI_Z2><<<dim3(4,64,1), 256, 0, stream>>>(dwT, wb_pw, z2T, nullptr,
      nullptr, nullptr, zT, nullptr, 8192, 512, 512, 0,0,0,0,0, 0.f);
  // 6. [u|v] = z2 @ [u_w|v_w]^T + b      (256-tile deep-pipe)
  gemm256<EPI_UV,256><<<dim3(8,32,1), 512, 0, stream>>>(z2T, wb_uv, ub, vT,
      u_b, v_b, nullptr, nullptr, 2048, 512, 0,0,0,0, 0.f, 0);
  // 7. h = z2 @ h_w^T + h_b              (128^2 deep-pipe)
  gemm_bt<EPI_BIAS><<<dim3(4,64,1), 256, 0, stream>>>(z2T, wb_h, hb, nullptr,
      h_b, nullptr, nullptr, nullptr, 8192, 512, 512, 0,0,0,0,0, 0.f);
  // 8. [q|k] = h @ [q_w|k_w]^T           (256x128 deep-pipe)
  gemm256<EPI_QK,128><<<dim3(8,32,1), 512, 0, stream>>>(hb, wb_qk, qb, kb,
      nullptr, nullptr, nullptr, nullptr, 1024, 512, 0,0,0,0, 0.f, 0);
  // 9. v -> feature-major [B,1024,2048]
  transpose_bf16<<<dim3(64,32,4), dim3(32,8), 0, stream>>>(vT, v_fm, 2048, 1024);
  // 10. w = relu(q@k^T * scale)^2 + fused row-sum atomics into rden
  gemm256<EPI_ATTN,256><<<dim3(8,8,4), 512, 0, stream>>>(qb, kb, wsc, rden,
      nullptr, nullptr, nullptr, nullptr, 2048, 512,
      (long)2048*512, (long)2048*512, (long)2048*2048, 2048, iscl, 0);
  // 11. uav = u * (w @ v_fm^T) / (den+eps)   (256x128 deep-pipe, batch in M)
  gemm256<EPI_PV,128><<<dim3(8,32,1), 512, 0, stream>>>(wsc, v_fm, uav, nullptr,
      nullptr, nullptr, ub, rden, 1024, 2048,
      0, (long)1024*2048, 0, 0, 0.f, 11);
  // 12. yT = uav @ o_w^T + o_b (bf16 token-major)   (128^2 deep-pipe)
  gemm_bt<EPI_Y><<<dim3(4,64,1), 256, 0, stream>>>(uav, wb_o, yT, nullptr,
      o_b, nullptr, nullptr, nullptr, 8192, 512, 1024, 0,0,0,0,0, 0.f);
  // 13. out = x + yT^T
  final_add<<<dim3(64,16,4), dim3(32,8), 0, stream>>>(x, yT, out);
}

// Round 6
// 208.311 us; speedup vs baseline: 1.1979x; 1.0642x over previous
//
#include <hip/hip_runtime.h>
#include <hip/hip_bf16.h>
#include <cstdint>

typedef __bf16 bhalf;
typedef __bf16 bhalf8 __attribute__((ext_vector_type(8)));
typedef float f32x4 __attribute__((ext_vector_type(4)));

enum { EPI_Z2=0, EPI_UV=1, EPI_BIAS=2, EPI_QK=3, EPI_ATTN=4, EPI_PV=5, EPI_Y=6 };

// async global->LDS, 16B per lane, LDS dest = wave-uniform base + lane*16
__device__ __forceinline__ void gl_lds16(const bhalf* g, bhalf* l) {
  __builtin_amdgcn_global_load_lds(
      (const __attribute__((address_space(1))) unsigned int*)g,
      (__attribute__((address_space(3))) unsigned int*)l,
      16, 0, 0);
}
__device__ __forceinline__ void barrier_raw() { asm volatile("s_barrier" ::: "memory"); }
#define VMW(n)  asm volatile("s_waitcnt vmcnt(" #n ")" ::: "memory")
#define LGKM0() asm volatile("s_waitcnt lgkmcnt(0)" ::: "memory")

// Staging bank swizzle (verified R4: SQ_LDS_BANK_CONFLICT == 0): 16B chunk c of
// a 64B row r holds global chunk c ^ ((r>>1)&3). Write: pre-swizzled GLOBAL
// source, linear LDS dest (rule #21); read: kqs = kq ^ ((lm>>1)&3).
// Epilogue C-tile swizzle: 32B chunk ^ ((row>>2)&3) on a 256B row.

// ---------------------------------------------------------------------------
// Deep-pipelined MFMA GEMM: out[m,n] = epi( sum_k A[m,k] * Bw[n,k] )
// 256x128 tile, BK=32, 8 waves (2x4), 3 LDS buffers (72KB -> 2 blocks/CU),
// 2-ahead prefetch, counted vmcnt, LDS-staged coalesced epilogue.
// ---------------------------------------------------------------------------
template<int EPI>
__global__ void __launch_bounds__(512, 4)
gemm256(const bhalf* __restrict__ A, const bhalf* __restrict__ Bw,
        void* __restrict__ Out, void* __restrict__ Out2,
        const float* __restrict__ bias, const float* __restrict__ bias2,
        const bhalf* __restrict__ auxb, const float* __restrict__ auxf,
        int N, int K, long sA, long sB, long sO, long sAuxf,
        float scale, int rowshift)
{
  constexpr int ABUF = 256*64;        // 16 KB
  constexpr int BBUF = 128*64;        // 8 KB
  constexpr int STRIDE = ABUF + BBUF; // 24 KB
  __shared__ __align__(16) char lds[3*STRIDE];   // 72 KB -> 2 blocks/CU

  // XCD-aware bijective swizzle (m204)
  const int gx = gridDim.x, gy = gridDim.y;
  const int nwg = gx*gy;
  const int flat = blockIdx.y*gx + blockIdx.x;
  const int q8 = nwg>>3, r8 = nwg&7, xcd = flat&7, o8 = flat>>3;
  const int wsw = (xcd<r8 ? xcd*(q8+1) : r8*(q8+1)+(xcd-r8)*q8) + o8;
  const int bx = wsw % gx, by = wsw / gx;
  const int m0 = by*256, n0 = bx*128;
  const int bz = blockIdx.z;

  const bhalf* Ab = A + (long)bz*sA;
  const bhalf* Bb = Bw + (rowshift ? (long)(m0>>rowshift)*sB : (long)bz*sB);

  const int tid = threadIdx.x, wid = tid>>6, lane = tid&63;
  const int lm = lane&15, kq = lane>>4;
  const int wm = wid>>2, wn = wid&3;
  const int srow = lane>>2;
  const int csw = ((lane&3) ^ ((lane>>3)&3)) * 8;   // pre-swizzled source chunk
  const int kqs = kq ^ ((lm>>1)&3);                 // swizzled read chunk

  f32x4 acc[8][2];
  #pragma unroll
  for (int i=0;i<8;i++)
    #pragma unroll
    for (int j=0;j<2;j++) acc[i][j] = f32x4{0.f,0.f,0.f,0.f};

  auto stage = [&](int buf, int t){
    char* base = lds + buf*STRIDE;
    const int k0 = t*32;
    #pragma unroll
    for (int c=0;c<2;c++){
      bhalf* d = (bhalf*)(base + (wid*32 + c*16)*64);
      gl_lds16(Ab + (long)(m0 + wid*32 + c*16 + srow)*K + k0 + csw, d);
    }
    bhalf* d = (bhalf*)(base + ABUF + (wid*16)*64);
    gl_lds16(Bb + (long)(n0 + wid*16 + srow)*K + k0 + csw, d);
  };

  auto compute = [&](int buf){
    char* base = lds + buf*STRIDE;
    bhalf8 af[8], bf[2];
    #pragma unroll
    for (int i=0;i<8;i++)
      af[i] = *(const bhalf8*)(base + (wm*128 + i*16 + lm)*64 + kqs*16);
    #pragma unroll
    for (int j=0;j<2;j++)
      bf[j] = *(const bhalf8*)(base + ABUF + (wn*32 + j*16 + lm)*64 + kqs*16);
    __builtin_amdgcn_s_setprio(1);
    #pragma unroll
    for (int i=0;i<8;i++)
      #pragma unroll
      for (int j=0;j<2;j++)
        acc[i][j] = __builtin_amdgcn_mfma_f32_16x16x32_bf16(af[i], bf[j], acc[i][j], 0,0,0);
    __builtin_amdgcn_s_setprio(0);
  };

  const int NT = K>>5;                 // BK=32, L=3 loads/wave/tile
  stage(0,0); stage(1,1);              // 2 tiles in flight
  int b0 = 0;
  for (int t=0; t<NT; ++t){
    if (t+2<NT){
      int b2 = b0+2; if (b2>=3) b2-=3;
      stage(b2, t+2);
      VMW(6);
    } else if (t+1<NT) { VMW(3); }
    else               { VMW(0); }
    barrier_raw();
    compute(b0);
    barrier_raw();
    if (++b0==3) b0=0;
  }

  // ---- epilogue: transform -> LDS C-tile (swizzled) -> coalesced stores ----
  char* obase; int ldb;
  const float* bv = nullptr; int bc0 = 0; bool sig = false;
  if constexpr (EPI==EPI_ATTN){
    obase = (char*)Out + 2*((long)bz*sO + (long)m0*N + n0); ldb = N*2;
  }
  if constexpr (EPI==EPI_PV){
    obase = (char*)Out + 2*((long)m0*1024 + n0); ldb = 2048;
  }
  if constexpr (EPI==EPI_UV){
    bool uh = n0 < 1024; sig = uh;
    obase = (char*)(uh?Out:Out2) + 2*((long)m0*1024 + (n0 - (uh?0:1024)));
    ldb = 2048; bv = uh ? bias : bias2; bc0 = uh ? n0 : n0-1024;
  }
  if constexpr (EPI==EPI_QK){
    bool qh = n0 < 512;
    obase = (char*)(qh?Out:Out2) + 2*((long)m0*512 + (n0 - (qh?0:512)));
    ldb = 1024;
  }

  float rs[8][4];
  if constexpr (EPI==EPI_ATTN){
    #pragma unroll
    for (int i=0;i<8;i++)
      #pragma unroll
      for (int r=0;r<4;r++) rs[i][r]=0.f;
  }
  #pragma unroll
  for (int i=0;i<8;i++){
    #pragma unroll
    for (int j=0;j<2;j++){
      const int lcol = wn*32 + j*16 + lm;
      #pragma unroll
      for (int r=0;r<4;r++){
        const int lrow = wm*128 + i*16 + kq*4 + r;
        float v = acc[i][j][r];
        if constexpr (EPI==EPI_ATTN){
          v *= scale; v = fmaxf(v,0.f); v = v*v;
          rs[i][r] += v;
        }
        if constexpr (EPI==EPI_PV){
          const int rowg = m0 + lrow;
          float den = auxf[rowg];
          v *= __builtin_amdgcn_rcpf(den + 1e-8f);
          v *= (float)auxb[(long)rowg*1024 + n0 + lcol];
        }
        if constexpr (EPI==EPI_UV){
          v += bv[bc0 + lcol];
          if (sig) v = 1.f/(1.f + __expf(-v));
        }
        const int cb = lcol*2;
        const int lb = lrow*256 + (((cb>>5) ^ ((lrow>>2)&3))<<5) + (cb&31);
        *(bhalf*)(lds + lb) = (bhalf)v;
      }
    }
  }
  if constexpr (EPI==EPI_ATTN){
    float* rd = (float*)Out2;
    #pragma unroll
    for (int i=0;i<8;i++){
      const int rbase = m0 + wm*128 + i*16 + kq*4;
      #pragma unroll
      for (int r=0;r<4;r++){
        float s = rs[i][r];
        s += __shfl_xor(s,1); s += __shfl_xor(s,2);
        s += __shfl_xor(s,4); s += __shfl_xor(s,8);
        if (lm==0) atomicAdd(rd + (long)bz*sAuxf + rbase + r, s);
      }
    }
  }
  LGKM0();
  barrier_raw();
  #pragma unroll
  for (int it=0; it<8; ++it){
    const int g = (it*512 + tid)*16;
    const int row = g >> 8, off = g & 255;
    const int lb = row*256 + (((off>>5) ^ ((row>>2)&3))<<5) + (off&31);
    uint4 val = *(const uint4*)(lds + lb);
    *(uint4*)(obase + (long)row*ldb + off) = val;
  }
  (void)scale; (void)bias; (void)bias2; (void)auxb; (void)auxf; (void)N;
}

// ---------------------------------------------------------------------------
// Deep-pipelined 128x128 GEMM (z2, h, y): BK=32, 4 buffers, 3-ahead, 64KB LDS
// -> 2 blocks/CU; LDS-staged coalesced epilogue.
// ---------------------------------------------------------------------------
template<int EPI>
__global__ void __launch_bounds__(256, 2)
gemm_bt(const bhalf* __restrict__ A, const bhalf* __restrict__ Bw,
        void* __restrict__ Out,
        const float* __restrict__ bias,
        const bhalf* __restrict__ auxb,
        int M, int N, int K, long sA, long sB)
{
  constexpr int ABUF = 128*64;        // 8 KB
  constexpr int STRIDE = 2*ABUF;      // 16 KB
  __shared__ __align__(16) char lds[4*STRIDE];

  const int bz = blockIdx.z;
  const int gx = gridDim.x, gy = gridDim.y;
  const int nwg = gx*gy;
  const int flat = blockIdx.y*gx + blockIdx.x;
  const int q8 = nwg>>3, r8 = nwg&7, xcd = flat&7, o8 = flat>>3;
  const int w = (xcd<r8 ? xcd*(q8+1) : r8*(q8+1)+(xcd-r8)*q8) + o8;
  const int bx = w % gx, by = w / gx;

  const bhalf* Ab = A + (long)bz*sA;
  const bhalf* Bb = Bw + (long)bz*sB;
  const int tid = threadIdx.x;
  const int wid = tid>>6, lane = tid&63;
  const int lm = lane&15, kq = lane>>4;
  const int wr = (wid>>1)*64, wc = (wid&1)*64;
  const int m0 = by*128, n0 = bx*128;
  const int srow = lane>>2;
  const int csw = ((lane&3) ^ ((lane>>3)&3))*8;
  const int kqs = kq ^ ((lm>>1)&3);

  f32x4 acc[4][4];
  #pragma unroll
  for (int i=0;i<4;i++)
    #pragma unroll
    for (int j=0;j<4;j++) acc[i][j] = f32x4{0.f,0.f,0.f,0.f};

  auto stage = [&](int t){
    char* base = lds + (t&3)*STRIDE;
    const int k0 = t*32;
    #pragma unroll
    for (int c=0;c<2;c++){
      bhalf* dA = (bhalf*)(base + (wid*32 + c*16)*64);
      gl_lds16(Ab + (long)(m0 + wid*32 + c*16 + srow)*K + k0 + csw, dA);
      bhalf* dB = (bhalf*)(base + ABUF + (wid*32 + c*16)*64);
      gl_lds16(Bb + (long)(n0 + wid*32 + c*16 + srow)*K + k0 + csw, dB);
    }
  };

  auto compute = [&](int t){
    char* base = lds + (t&3)*STRIDE;
    bhalf8 af[4], bf[4];
    #pragma unroll
    for (int i=0;i<4;i++)
      af[i] = *(const bhalf8*)(base + (wr + i*16 + lm)*64 + kqs*16);
    #pragma unroll
    for (int j=0;j<4;j++)
      bf[j] = *(const bhalf8*)(base + ABUF + (wc + j*16 + lm)*64 + kqs*16);
    __builtin_amdgcn_s_setprio(1);
    #pragma unroll
    for (int i=0;i<4;i++)
      #pragma unroll
      for (int j=0;j<4;j++)
        acc[i][j] = __builtin_amdgcn_mfma_f32_16x16x32_bf16(af[i], bf[j], acc[i][j], 0,0,0);
    __builtin_amdgcn_s_setprio(0);
  };

  const int NT = K>>5;
  stage(0); stage(1); stage(2);
  for (int t=0; t<NT; ++t){
    if (t+3<NT){ stage(t+3); VMW(12); }
    else if (t+2<NT) { VMW(8); }
    else if (t+1<NT) { VMW(4); }
    else             { VMW(0); }
    barrier_raw();
    compute(t);
    barrier_raw();
  }

  // ---- coalesced epilogue via LDS C-tile (32KB) ----
  char* obase = (char*)Out + 2*((long)m0*N + n0);
  const int ldb = N*2;
  #pragma unroll
  for (int i=0;i<4;i++){
    #pragma unroll
    for (int j=0;j<4;j++){
      const int lcol = wc + j*16 + lm;
      #pragma unroll
      for (int r=0;r<4;r++){
        const int lrow = wr + i*16 + kq*4 + r;
        float v = acc[i][j][r];
        if constexpr (EPI==EPI_Z2)
          v += (float)auxb[(long)(m0+lrow)*N + n0 + lcol];
        if constexpr (EPI==EPI_BIAS || EPI==EPI_Y)
          v += bias[n0 + lcol];
        const int cb = lcol*2;
        const int lb = lrow*256 + (((cb>>5) ^ ((lrow>>2)&3))<<5) + (cb&31);
        *(bhalf*)(lds + lb) = (bhalf)v;
      }
    }
  }
  LGKM0();
  barrier_raw();
  #pragma unroll
  for (int it=0; it<8; ++it){
    const int g = (it*256 + tid)*16;
    const int row = g >> 8, off = g & 255;
    const int lb = row*256 + (((off>>5) ^ ((row>>2)&3))<<5) + (off&31);
    uint4 val = *(const uint4*)(lds + lb);
    *(uint4*)(obase + (long)row*ldb + off) = val;
  }
  (void)M;
}

// ---------------------------------------------------------------------------
struct CvtArgs { const float* src[7]; bhalf* dst[7]; int n[7]; };
__global__ void cvt_multi(CvtArgs a) {
  int seg = blockIdx.y;
  int i = (blockIdx.x*256 + threadIdx.x)*4;
  if (i >= a.n[seg]) return;
  float4 f = *(const float4*)(a.src[seg] + i);
  bhalf* d = a.dst[seg] + i;
  d[0]=(bhalf)f.x; d[1]=(bhalf)f.y; d[2]=(bhalf)f.z; d[3]=(bhalf)f.w;
}

__global__ void gn_part(const float* __restrict__ x, float* __restrict__ ps, float* __restrict__ pss) {
  int b = blockIdx.y;
  const float* xb = x + (long)b*(512*2048);
  float s=0.f, ss=0.f;
  #pragma unroll
  for (int it=0; it<8; it++){
    int idx = ((it*128 + blockIdx.x)*256 + threadIdx.x)*4;
    float4 f = *(const float4*)(xb + idx);
    s  += f.x+f.y+f.z+f.w;
    ss += f.x*f.x+f.y*f.y+f.z*f.z+f.w*f.w;
  }
  for (int off=32; off; off>>=1){ s += __shfl_xor(s,off); ss += __shfl_xor(ss,off); }
  __shared__ float ls[4], lss[4];
  int wid = threadIdx.x>>6, lane = threadIdx.x&63;
  if (lane==0){ ls[wid]=s; lss[wid]=ss; }
  __syncthreads();
  if (threadIdx.x==0){
    s = ls[0]+ls[1]+ls[2]+ls[3]; ss = lss[0]+lss[1]+lss[2]+lss[3];
    ps[b*128 + blockIdx.x] = s; pss[b*128 + blockIdx.x] = ss;
  }
}

__global__ void gn_final(const float* __restrict__ ps, const float* __restrict__ pss,
                         float* __restrict__ stats) {
  int b = blockIdx.x;
  float s = ps[b*128 + threadIdx.x], ss = pss[b*128 + threadIdx.x];
  for (int off=32; off; off>>=1){ s += __shfl_xor(s,off); ss += __shfl_xor(ss,off); }
  __shared__ float l0[2], l1[2];
  int wid = threadIdx.x>>6, lane = threadIdx.x&63;
  if (lane==0){ l0[wid]=s; l1[wid]=ss; }
  __syncthreads();
  if (threadIdx.x==0){
    s = l0[0]+l0[1]; ss = l1[0]+l1[1];
    float mean = s*(1.f/1048576.f);
    float var  = ss*(1.f/1048576.f) - mean*mean;
    stats[b*2] = mean; stats[b*2+1] = rsqrtf(var + 1e-8f);
  }
}

__global__ void norm_dw_T(const float* __restrict__ x, const float* __restrict__ stats,
                          const float* __restrict__ dw_w,
                          bhalf* __restrict__ zT, bhalf* __restrict__ dwT) {
  int b = blockIdx.z, n0 = blockIdx.x*32, c0 = blockIdx.y*32;
  float mean = stats[b*2], rstd = stats[b*2+1];
  __shared__ float zs[32][35];
  int tx = threadIdx.x, ty = threadIdx.y;
  #pragma unroll
  for (int r=0;r<4;r++){
    int c = c0 + ty + r*8;
    for (int cc=tx; cc<34; cc+=32){
      int n = n0 - 1 + cc;
      float v = 0.f;
      if (n>=0 && n<2048) v = (x[((long)b*512 + c)*2048 + n] - mean)*rstd;
      zs[ty + r*8][cc] = v;
    }
  }
  __syncthreads();
  float w0 = dw_w[(c0+tx)*3+0], w1 = dw_w[(c0+tx)*3+1], w2 = dw_w[(c0+tx)*3+2];
  #pragma unroll
  for (int r=0;r<4;r++){
    int ln = ty + r*8;
    float z = zs[tx][ln+1];
    float d = w0*zs[tx][ln] + w1*zs[tx][ln+1] + w2*zs[tx][ln+2];
    long o = ((long)b*2048 + n0 + ln)*512 + c0 + tx;
    zT[o] = (bhalf)z; dwT[o] = (bhalf)d;
  }
}

__global__ void transpose_bf16(const bhalf* __restrict__ in, bhalf* __restrict__ out,
                               int R, int C) {
  __shared__ bhalf t[32][33];
  int r0 = blockIdx.x*32, c0 = blockIdx.y*32;
  long ib = (long)blockIdx.z*R*C;
  int tx = threadIdx.x, ty = threadIdx.y;
  #pragma unroll
  for (int r=0;r<4;r++)
    t[ty + r*8][tx] = in[ib + (long)(r0 + ty + r*8)*C + c0 + tx];
  __syncthreads();
  #pragma unroll
  for (int r=0;r<4;r++)
    out[ib + (long)(c0 + ty + r*8)*R + r0 + tx] = t[tx][ty + r*8];
}

__global__ void final_add(const float* __restrict__ x, const bhalf* __restrict__ yT,
                          float* __restrict__ out) {
  __shared__ float t[32][33];
  int n0 = blockIdx.x*32, c0 = blockIdx.y*32, b = blockIdx.z;
  int tx = threadIdx.x, ty = threadIdx.y;
  #pragma unroll
  for (int r=0;r<4;r++)
    t[ty + r*8][tx] = (float)yT[((long)b*2048 + n0 + ty + r*8)*512 + c0 + tx];
  __syncthreads();
  #pragma unroll
  for (int r=0;r<4;r++){
    long idx = ((long)b*512 + c0 + ty + r*8)*2048 + n0 + tx;
    out[idx] = x[idx] + t[tx][ty + r*8];
  }
}

// ---------------------------------------------------------------------------
extern "C" void kernel_launch(void* const* d_in, const int* in_sizes, int n_in,
                              void* d_out, int out_size, void* d_ws, size_t ws_size,
                              hipStream_t stream) {
  (void)in_sizes; (void)n_in; (void)out_size; (void)ws_size;
  const float* x    = (const float*)d_in[0];
  const float* dw_w = (const float*)d_in[1];
  const float* pw_w = (const float*)d_in[2];
  const float* u_w  = (const float*)d_in[3];
  const float* u_b  = (const float*)d_in[4];
  const float* v_w  = (const float*)d_in[5];
  const float* v_b  = (const float*)d_in[6];
  const float* h_w  = (const float*)d_in[7];
  const float* h_b  = (const float*)d_in[8];
  const float* q_w  = (const float*)d_in[9];
  const float* k_w  = (const float*)d_in[10];
  const float* o_w  = (const float*)d_in[11];
  const float* o_b  = (const float*)d_in[12];
  float* out = (float*)d_out;

  char* ws = (char*)d_ws;
  size_t off = 0;
  auto alloc = [&](size_t bytes) -> void* {
    void* p = ws + off; off = (off + bytes + 255) & ~(size_t)255; return p;
  };

  float* ps    = (float*)alloc(4*128*4);
  float* pss   = (float*)alloc(4*128*4);
  float* stats = (float*)alloc(4*2*4);
  float* rden  = (float*)alloc(4*2048*4);
  bhalf* wb_pw = (bhalf*)alloc(512*512*2);
  bhalf* wb_uv = (bhalf*)alloc((size_t)2048*512*2);
  bhalf* wb_h  = (bhalf*)alloc(512*512*2);
  bhalf* wb_qk = (bhalf*)alloc((size_t)1024*512*2);
  bhalf* wb_o  = (bhalf*)alloc((size_t)512*1024*2);
  const size_t ACT = (size_t)4*2048*512;
  bhalf* zT   = (bhalf*)alloc(ACT*2);       // reused as qb
  bhalf* dwT  = (bhalf*)alloc(ACT*2);       // reused as kb
  bhalf* z2T  = (bhalf*)alloc(ACT*2);
  bhalf* ub   = (bhalf*)alloc(ACT*2*2);     // [B,N,1024]
  bhalf* vT   = (bhalf*)alloc(ACT*2*2);     // reused as yT (bf16 [B,N,512])
  bhalf* v_fm = (bhalf*)alloc(ACT*2*2);     // [B,1024,2048]
  bhalf* hb   = (bhalf*)alloc(ACT*2);
  bhalf* wsc  = (bhalf*)alloc((size_t)4*2048*2048*2);
  bhalf* uav  = (bhalf*)alloc(ACT*2*2);
  bhalf* qb = zT;  bhalf* kb = dwT;  bhalf* yT = vT;

  // 0. zero attention-denominator accumulators
  hipMemsetAsync(rden, 0, 4*2048*4, stream);

  // 1. weights -> bf16 (u|v and q|k concatenated)
  CvtArgs ca;
  ca.src[0]=pw_w; ca.dst[0]=wb_pw;           ca.n[0]=512*512;
  ca.src[1]=u_w;  ca.dst[1]=wb_uv;           ca.n[1]=1024*512;
  ca.src[2]=v_w;  ca.dst[2]=wb_uv+1024*512;  ca.n[2]=1024*512;
  ca.src[3]=h_w;  ca.dst[3]=wb_h;            ca.n[3]=512*512;
  ca.src[4]=q_w;  ca.dst[4]=wb_qk;           ca.n[4]=512*512;
  ca.src[5]=k_w;  ca.dst[5]=wb_qk+512*512;   ca.n[5]=512*512;
  ca.src[6]=o_w;  ca.dst[6]=wb_o;            ca.n[6]=512*1024;
  cvt_multi<<<dim3(512,7), 256, 0, stream>>>(ca);

  // 2-3. GroupNorm stats
  gn_part<<<dim3(128,4), 256, 0, stream>>>(x, ps, pss);
  gn_final<<<dim3(4), 128, 0, stream>>>(ps, pss, stats);

  // 4. normalize + dw conv + transpose -> zT, dwT
  norm_dw_T<<<dim3(64,16,4), dim3(32,8), 0, stream>>>(x, stats, dw_w, zT, dwT);

  const float iscl = 0.044194173824159216f;   // 1/sqrt(512)
  // 5. z2 = z + dw @ pw^T                (128^2, 2 blocks/CU)
  gemm_bt<EPI_Z2><<<dim3(4,64,1), 256, 0, stream>>>(dwT, wb_pw, z2T,
      nullptr, zT, 8192, 512, 512, 0, 0);
  // 6. [u|v] = z2 @ [u_w|v_w]^T + b      (256x128, 2 blocks/CU)
  gemm256<EPI_UV><<<dim3(16,32,1), 512, 0, stream>>>(z2T, wb_uv, ub, vT,
      u_b, v_b, nullptr, nullptr, 2048, 512, 0,0,0,0, 0.f, 0);
  // 7. h = z2 @ h_w^T + h_b
  gemm_bt<EPI_BIAS><<<dim3(4,64,1), 256, 0, stream>>>(z2T, wb_h, hb,
      h_b, nullptr, 8192, 512, 512, 0, 0);
  // 8. [q|k] = h @ [q_w|k_w]^T
  gemm256<EPI_QK><<<dim3(8,32,1), 512, 0, stream>>>(hb, wb_qk, qb, kb,
      nullptr, nullptr, nullptr, nullptr, 1024, 512, 0,0,0,0, 0.f, 0);
  // 9. v -> feature-major [B,1024,2048]
  transpose_bf16<<<dim3(64,32,4), dim3(32,8), 0, stream>>>(vT, v_fm, 2048, 1024);
  // 10. w = relu(q@k^T * scale)^2 + fused row-sum atomics into rden
  gemm256<EPI_ATTN><<<dim3(16,8,4), 512, 0, stream>>>(qb, kb, wsc, rden,
      nullptr, nullptr, nullptr, nullptr, 2048, 512,
      (long)2048*512, (long)2048*512, (long)2048*2048, 2048, iscl, 0);
  // 11. uav = u * (w @ v_fm^T) / (den+eps)   (batch folded into M)
  gemm256<EPI_PV><<<dim3(8,32,1), 512, 0, stream>>>(wsc, v_fm, uav, nullptr,
      nullptr, nullptr, ub, rden, 1024, 2048,
      0, (long)1024*2048, 0, 0, 0.f, 11);
  // 12. yT = uav @ o_w^T + o_b (bf16 token-major)
  gemm_bt<EPI_Y><<<dim3(4,64,1), 256, 0, stream>>>(uav, wb_o, yT,
      o_b, nullptr, 8192, 512, 1024, 0, 0);
  // 13. out = x + yT^T
  final_add<<<dim3(64,16,4), dim3(32,8), 0, stream>>>(x, yT, out);
}